// Round 9
// baseline (1059.632 us; speedup 1.0000x reference)
//
#include <hip/hip_runtime.h>
#include <math.h>

// Dims: B=8, NS=32, L=128, H=768, LH=256, C=4. N_SEQ=256, gates=1024.

typedef __bf16 bf16x8 __attribute__((ext_vector_type(8)));
typedef float  f32x4  __attribute__((ext_vector_type(4)));

__device__ __forceinline__ float sigmoidf_(float x){ return 1.0f/(1.0f+expf(-x)); }
__device__ __forceinline__ unsigned short f2bf(float x){
    unsigned int b = __float_as_uint(x);
    b += 0x7FFFu + ((b>>16)&1u);
    return (unsigned short)(b>>16);
}
__device__ __forceinline__ float bf2f(unsigned short h){
    return __uint_as_float(((unsigned int)h)<<16);
}
__device__ __forceinline__ void split_bf(float x, unsigned short &hi, unsigned short &lo){
    hi = f2bf(x);
    lo = f2bf(x - bf2f(hi));
}
__device__ __forceinline__ uint4 pack8(const unsigned short* s){
    uint4 u;
    u.x = (unsigned)s[0] | ((unsigned)s[1]<<16);
    u.y = (unsigned)s[2] | ((unsigned)s[3]<<16);
    u.z = (unsigned)s[4] | ((unsigned)s[5]<<16);
    u.w = (unsigned)s[6] | ((unsigned)s[7]<<16);
    return u;
}

// ---------------------------------------------------------------------------
// Counter-based AGENT-scope group barrier — empirically the fastest variant
// (r5/r7: 3.15us/step word incl. stage+compute; r6's epoch-flag was slower).
__device__ __forceinline__ void group_barrier(int* p, int members, int tid) {
    __syncthreads();   // drains vmcnt(0): all threads' stores complete
    if (tid == 0) {
        __hip_atomic_fetch_add(p, 1, __ATOMIC_RELAXED, __HIP_MEMORY_SCOPE_AGENT);
        int it = 0;
        while (__hip_atomic_load(p, __ATOMIC_RELAXED, __HIP_MEMORY_SCOPE_AGENT) < members) {
            __builtin_amdgcn_s_sleep(1);
            if (++it > (1<<22)) break;   // safety: degrade, don't hang
        }
    }
    __builtin_amdgcn_fence(__ATOMIC_ACQUIRE, "workgroup");  // compile-order only
    __syncthreads();
}

// self-test pattern: round 1 is the bitwise inverse of round 0, so a stale
// read (L1, foreign L2, or previous launch) can never match both rounds.
__device__ __forceinline__ unsigned tpat(int bid, int tid, int r) {
    unsigned v = (unsigned)bid * 1315423911u ^ (unsigned)tid * 2654435761u ^ 0x9E3779B9u;
    return r ? ~v : v;
}

// ---------------------------------------------------------------------------
__global__ void zero_f4(float4* __restrict__ p, int n) {
    int i = blockIdx.x * 256 + threadIdx.x;
    if (i < n) p[i] = make_float4(0.f, 0.f, 0.f, 0.f);
}

// ---------------------------------------------------------------------------
// X (32768x768 fp32) -> hi/lo bf16 frag-swizzled blocks.
__global__ void prep_x(const float* __restrict__ X, unsigned short* __restrict__ Xsw) {
    int idx = blockIdx.x * 256 + threadIdx.x;
    int gblk = idx >> 6, ln = idx & 63;
    int mt = gblk / 24, kb = gblk - mt * 24;
    int m = mt * 16 + (ln & 15);
    int k = kb * 32 + (ln >> 4) * 8;
    const float* xp = X + (size_t)m * 768 + k;
    unsigned short hi[8], lo[8];
#pragma unroll
    for (int e = 0; e < 8; e += 4) {
        float4 v = *(const float4*)(xp + e);
        split_bf(v.x, hi[e+0], lo[e+0]);
        split_bf(v.y, hi[e+1], lo[e+1]);
        split_bf(v.z, hi[e+2], lo[e+2]);
        split_bf(v.w, hi[e+3], lo[e+3]);
    }
    *(uint4*)&Xsw[(size_t)gblk*1024 + ln*8]       = pack8(hi);
    *(uint4*)&Xsw[(size_t)gblk*1024 + 512 + ln*8] = pack8(lo);
}

// ---------------------------------------------------------------------------
__global__ void prep_wih_sw(const float* __restrict__ Wf, const float* __restrict__ Wb,
                            unsigned short* __restrict__ Wsw) {
    int idx = blockIdx.x * 256 + threadIdx.x;
    int gblk = idx >> 6, ln = idx & 63;
    int dir = gblk / 1536;
    int rem = gblk - dir * 1536;
    int ntile = rem / 24, kb = rem - ntile * 24;
    int j = ntile * 16 + (ln & 15);
    int k = kb * 32 + (ln >> 4) * 8;
    const float* wp = (dir ? Wb : Wf) + (size_t)j * 768 + k;
    unsigned short hi[8], lo[8];
#pragma unroll
    for (int e = 0; e < 8; e += 4) {
        float4 v = *(const float4*)(wp + e);
        split_bf(v.x, hi[e+0], lo[e+0]);
        split_bf(v.y, hi[e+1], lo[e+1]);
        split_bf(v.z, hi[e+2], lo[e+2]);
        split_bf(v.w, hi[e+3], lo[e+3]);
    }
    *(uint4*)&Wsw[(size_t)gblk*1024 + ln*8]       = pack8(hi);
    *(uint4*)&Wsw[(size_t)gblk*1024 + 512 + ln*8] = pack8(lo);
}

// ---------------------------------------------------------------------------
// Word W_hh images: per (dir, u0t): [hi: 4g x 16u x 264][lo: same].
__global__ void prep_whh(const float* __restrict__ Wf, const float* __restrict__ Wb,
                         unsigned short* __restrict__ Wimg) {
    int idx = blockIdx.x * 256 + threadIdx.x;
    if (idx >= 524288) return;
    int dir = idx >> 18;
    int r   = idx & 262143;
    int u0t = r >> 14;
    int g   = (r >> 12) & 3;
    int u   = (r >> 8) & 15;
    int k   = r & 255;
    const float* W = dir ? Wb : Wf;
    float v = W[(size_t)(g*256 + u0t*16 + u) * 256 + k];
    unsigned short hi, lo; split_bf(v, hi, lo);
    size_t base = (size_t)(dir*16 + u0t) * 34816;
    Wimg[base + (g*16 + u)*264 + k]         = hi;
    Wimg[base + 16896 + (g*16 + u)*264 + k] = lo;
}

// ---------------------------------------------------------------------------
// Transpose sentence-level W_hh -> Wt[dir][k][j] (main path: launch-loop
// sentence stage).
__global__ void transpose_whh(const float* __restrict__ Wf, const float* __restrict__ Wb,
                              float* __restrict__ Wt) {
    int idx = blockIdx.x * 256 + threadIdx.x;
    if (idx >= 524288) return;
    int dir = idx >> 18;
    int rem = idx & 262143;
    int k = rem >> 10;
    int j = rem & 1023;
    const float* Wp = dir ? Wb : Wf;
    Wt[idx] = Wp[j * 256 + k];
}

// ---------------------------------------------------------------------------
// Word input projection — EXACT r7 form (252us measured). r8's XCD-band
// remap REVERTED: x-major dispatch already emits all 16 nt-blocks of one mt
// consecutively, which is the locality that matters; the remap broke it.
__global__ __launch_bounds__(256, 2) void proj_mfma(
    const unsigned short* __restrict__ Xsw,
    const unsigned short* __restrict__ Wihsw,
    const float* __restrict__ bfw, const float* __restrict__ bbw,
    float* __restrict__ Of, float* __restrict__ Ob)
{
    __shared__ unsigned short lds[24576];
    const int tid = threadIdx.x;
    const int nt = blockIdx.x;
    const int mt = blockIdx.y;
    const int sel = nt >> 3;
    const int ntl = nt & 7;
    const float* bias = sel ? bbw : bfw;
    float* Op = sel ? Ob : Of;
    const int wv = tid >> 6, ln = tid & 63;
    const int c = ln & 15, q = ln >> 4;

    f32x4 acc[4][8];
#pragma unroll
    for (int i = 0; i < 4; i++)
#pragma unroll
        for (int j = 0; j < 8; j++) acc[i][j] = f32x4{0.f,0.f,0.f,0.f};

    const unsigned short* Abase = Xsw + (size_t)(mt*16) * 24 * 1024;
    const unsigned short* Bbase = Wihsw + (size_t)(sel*64 + ntl*8) * 24 * 1024;

#pragma unroll 1
    for (int kb = 0; kb < 24; kb++) {
        __syncthreads();
#pragma unroll
        for (int jj = 0; jj < 12; jj++) {
            int cc = wv + 4*jj;
            int isB = (cc >= 32);
            int blk = isB ? ((cc - 32) >> 1) : (cc >> 1);
            int half = cc & 1;
            const unsigned short* src = (isB ? Bbase : Abase)
                                        + (size_t)(blk*24 + kb)*1024 + half*512 + ln*8;
            unsigned short* dst = lds + (isB ? 16384 : 0) + blk*1024 + half*512 + ln*8;
            __builtin_amdgcn_global_load_lds(
                (const __attribute__((address_space(1))) unsigned int*)src,
                (__attribute__((address_space(3))) unsigned int*)dst, 16, 0, 0);
        }
        __syncthreads();

        bf16x8 bhv[8], blv[8];
#pragma unroll
        for (int cb = 0; cb < 8; cb++) {
            bhv[cb] = *(const bf16x8*)&lds[16384 + cb*1024 + ln*8];
            blv[cb] = *(const bf16x8*)&lds[16384 + cb*1024 + 512 + ln*8];
        }
#pragma unroll
        for (int rb = 0; rb < 4; rb++) {
            int it = wv*4 + rb;
            bf16x8 ah = *(const bf16x8*)&lds[it*1024 + ln*8];
            bf16x8 al = *(const bf16x8*)&lds[it*1024 + 512 + ln*8];
#pragma unroll
            for (int cb = 0; cb < 8; cb++) {
                acc[rb][cb] = __builtin_amdgcn_mfma_f32_16x16x32_bf16(ah, bhv[cb], acc[rb][cb], 0,0,0);
                acc[rb][cb] = __builtin_amdgcn_mfma_f32_16x16x32_bf16(ah, blv[cb], acc[rb][cb], 0,0,0);
                acc[rb][cb] = __builtin_amdgcn_mfma_f32_16x16x32_bf16(al, bhv[cb], acc[rb][cb], 0,0,0);
            }
        }
    }

#pragma unroll
    for (int rb = 0; rb < 4; rb++) {
        int mbase = mt*256 + (wv*4 + rb)*16 + q*4;
#pragma unroll
        for (int cb = 0; cb < 8; cb++) {
            int j = ntl*128 + cb*16 + c;
            float bv = bias[j];
#pragma unroll
            for (int reg = 0; reg < 4; reg++) {
                int m = mbase + reg;
                int tt = m & 127, nn = m >> 7;
                Op[(size_t)(tt*256 + nn)*1024 + j] = acc[rb][cb][reg] + bv;
            }
        }
    }
}

// ---------------------------------------------------------------------------
// PERSISTENT word recurrence (unchanged from r7: 400us measured). PLAIN
// launch; per-step sync = counter barrier; producers agent atomic stores;
// consumer fast path = global_load_lds aux=0x11 (L1+L2 bypass, reads L3),
// self-tested at startup; fallback = 8B agent atomics. Pool norm fused.
__global__ __launch_bounds__(256, 1) void word_recur(
    const float* __restrict__ Gf, const float* __restrict__ Gb,
    const unsigned short* __restrict__ Wimg,
    unsigned short* __restrict__ hA, unsigned short* __restrict__ hB,
    const int* __restrict__ mask,
    float* __restrict__ pooled, int* __restrict__ cnt,
    int* __restrict__ pf, unsigned int* __restrict__ tstg)
{
    extern __shared__ char ldsbuf[];
    unsigned short* Hl = (unsigned short*)ldsbuf;            // 36864 B
    float* gex   = (float*)(ldsbuf + 36864);                 // 9216 B  [4][16][36]
    int*   mk_lds= (int*)(ldsbuf + 46080);                   // 16384 B [32 seq][128 t]
    // total 62464 B

    const int tid = threadIdx.x;
    const int bid = blockIdx.x;
    const int dir = (bid >> 3) & 1;
    const int nt  = bid & 7;
    const int u0t = bid >> 4;
    const int grp = bid & 15;
    const float* G = dir ? Gb : Gf;

    const int wv = tid >> 6, ln = tid & 63;
    const int c = ln & 15, q = ln >> 4;

    int* mycnt = cnt + grp * 136;   // slots 0..126 = steps, 127..131 = self-test

    // ---- self-test of the fast consumer path (slots 127..131):
    //      agent atomic store -> agent barrier -> load_lds aux=0x11 ----
    bool fast;
    {
        unsigned* tl = (unsigned*)ldsbuf;         // [4][256] staged partner data
        int* oks = (int*)(ldsbuf + 4096);         // [256]
        int okl = 1;
#pragma unroll 1
        for (int r = 0; r < 2; r++) {
            __hip_atomic_store(&tstg[bid*256 + tid], tpat(bid, tid, r),
                               __ATOMIC_RELAXED, __HIP_MEMORY_SCOPE_AGENT);
            group_barrier(mycnt + 127 + 2*r, 16, tid);          // all wrote
            {
                int pbid = grp + 16*((u0t + 1 + wv) & 15);
                __builtin_amdgcn_global_load_lds(
                    (const __attribute__((address_space(1))) unsigned int*)
                        ((const char*)(tstg + pbid*256) + ln*16),
                    (__attribute__((address_space(3))) unsigned int*)(ldsbuf + wv*1024),
                    16, 0, 0x11 /* SC0|SC1: L1+L2 bypass */);
            }
            __syncthreads();
#pragma unroll
            for (int w2 = 0; w2 < 4; w2++) {
                int pb2 = grp + 16*((u0t + 1 + w2) & 15);
                okl &= (tl[w2*256 + tid] == tpat(pb2, tid, r)) ? 1 : 0;
            }
            group_barrier(mycnt + 128 + 2*r, 16, tid);          // all read
        }
        oks[tid] = okl;
        __syncthreads();
        if (tid == 0) {
            int o = 1;
            for (int i = 0; i < 256; i++) o &= oks[i];
            __hip_atomic_store(&pf[bid], o, __ATOMIC_RELAXED, __HIP_MEMORY_SCOPE_AGENT);
        }
        group_barrier(mycnt + 131, 16, tid);
        int f = 1;
#pragma unroll 1
        for (int k = 0; k < 16; k++)
            f &= __hip_atomic_load(&pf[grp + 16*k],
                                   __ATOMIC_RELAXED, __HIP_MEMORY_SCOPE_AGENT);
        fast = (f != 0);
    }

    // ---- one-time: stage mask rows into LDS ----
    {
        const char* msrc = (const char*)(mask + nt*32*128);
#pragma unroll
        for (int j = 0; j < 4; j++) {
            int i = wv + 4*j;
            __builtin_amdgcn_global_load_lds(
                (const __attribute__((address_space(1))) unsigned int*)(msrc + i*1024 + ln*16),
                (__attribute__((address_space(3))) unsigned int*)(((char*)mk_lds) + i*1024), 16, 0, 0);
        }
    }
    // ---- one-time: W fragments (loop-invariant) ----
    const unsigned short* wbase = Wimg + (size_t)(dir*16 + u0t) * 34816;
    bf16x8 wh_[8], wlo[8];
#pragma unroll
    for (int kb = 0; kb < 8; kb++) {
        wh_[kb] = *(const bf16x8*)&wbase[(wv*16 + c)*264 + kb*32 + q*8];
        wlo[kb] = *(const bf16x8*)&wbase[16896 + (wv*16 + c)*264 + kb*32 + q*8];
    }

    // cell-update mapping: thread owns (seq nl, unit pair up)
    const int nl  = tid >> 3;            // 0..31
    const int up  = tid & 7;             // 0..7 -> units 2*up, 2*up+1
    const int u0  = up*2;
    const int ug0 = u0t*16 + u0;
    const int n   = nt*32 + nl;

    float c0 = 0.f, c1 = 0.f, p0 = 0.f, p1 = 0.f;

    // G prefetch for t = 0
    float2 gp[4];
    {
        const int te0 = dir ? 127 : 0;
        const float* Ga = G + (size_t)(te0*256 + n)*1024 + ug0;
#pragma unroll
        for (int g = 0; g < 4; g++) gp[g] = *(const float2*)&Ga[g*256];
    }

#pragma unroll 1
    for (int t = 0; t < 128; ++t) {
        const int te = dir ? (127 - t) : t;
        const unsigned short* hin = (t & 1) ? hB : hA;
        unsigned short* hout = ((t & 1) ? hA : hB) + (size_t)(dir*8 + nt) * 18432;

        // stage h image (36 KB)
        if (fast) {
            const char* hsrc = (const char*)(hin + (size_t)(dir*8 + nt) * 18432);
#pragma unroll
            for (int j = 0; j < 9; j++) {
                int i = wv + 4*j;
                __builtin_amdgcn_global_load_lds(
                    (const __attribute__((address_space(1))) unsigned int*)(hsrc + i*1024 + ln*16),
                    (__attribute__((address_space(3))) unsigned int*)(ldsbuf + i*1024),
                    16, 0, 0x11 /* SC0|SC1 */);
            }
        } else {
            const unsigned long long* hsrc =
                (const unsigned long long*)(hin + (size_t)(dir*8 + nt) * 18432);
            unsigned long long* hdst = (unsigned long long*)ldsbuf;
#pragma unroll
            for (int j = 0; j < 18; j++) {
                unsigned long long v = __hip_atomic_load(hsrc + tid + 256*j,
                        __ATOMIC_RELAXED, __HIP_MEMORY_SCOPE_AGENT);
                hdst[tid + 256*j] = v;
            }
        }
        __syncthreads();   // staging complete

        f32x4 acc[2];
        acc[0] = f32x4{0.f,0.f,0.f,0.f};
        acc[1] = f32x4{0.f,0.f,0.f,0.f};
#pragma unroll
        for (int kb = 0; kb < 8; kb++) {
#pragma unroll
            for (int sb = 0; sb < 2; sb++) {
                bf16x8 bh = *(const bf16x8*)&Hl[(sb*16 + c)*264 + kb*32 + q*8];
                bf16x8 bl = *(const bf16x8*)&Hl[8448 + (sb*16 + c)*264 + kb*32 + q*8];
                acc[sb] = __builtin_amdgcn_mfma_f32_16x16x32_bf16(wh_[kb], bh, acc[sb], 0, 0, 0);
                acc[sb] = __builtin_amdgcn_mfma_f32_16x16x32_bf16(wh_[kb], bl, acc[sb], 0, 0, 0);
                acc[sb] = __builtin_amdgcn_mfma_f32_16x16x32_bf16(wlo[kb], bh, acc[sb], 0, 0, 0);
            }
        }
#pragma unroll
        for (int sb = 0; sb < 2; sb++)
#pragma unroll
            for (int reg = 0; reg < 4; reg++)
                gex[(wv*16 + q*4 + reg)*36 + sb*16 + c] = acc[sb][reg];
        __syncthreads();

        // G prefetch for t+1: issued here so HBM latency hides under the
        // cell-update transcendentals.
        float2 gpn[4];
        if (t < 127) {
            const int te1 = dir ? (126 - t) : (t + 1);
            const float* Ga = G + (size_t)(te1*256 + n)*1024 + ug0;
#pragma unroll
            for (int g = 0; g < 4; g++) gpn[g] = *(const float2*)&Ga[g*256];
        }

        // ---- cell update: (nl, u0) and (nl, u0+1), state in registers ----
        const int mk = mk_lds[nl*128 + te];
        float iv0 = gex[(0*16 + u0)*36 + nl] + gp[0].x;
        float fv0 = gex[(1*16 + u0)*36 + nl] + gp[1].x;
        float gv0 = gex[(2*16 + u0)*36 + nl] + gp[2].x;
        float ov0 = gex[(3*16 + u0)*36 + nl] + gp[3].x;
        float iv1 = gex[(0*16 + u0+1)*36 + nl] + gp[0].y;
        float fv1 = gex[(1*16 + u0+1)*36 + nl] + gp[1].y;
        float gv1 = gex[(2*16 + u0+1)*36 + nl] + gp[2].y;
        float ov1 = gex[(3*16 + u0+1)*36 + nl] + gp[3].y;
        float cn0 = sigmoidf_(fv0)*c0 + sigmoidf_(iv0)*tanhf(gv0);
        float hn0 = sigmoidf_(ov0)*tanhf(cn0);
        float cn1 = sigmoidf_(fv1)*c1 + sigmoidf_(iv1)*tanhf(gv1);
        float hn1 = sigmoidf_(ov1)*tanhf(cn1);
        c0 = cn0; c1 = cn1;
        if (mk) { p0 += hn0; p1 += hn1; }
        if (t != 127) {
            unsigned short h0h, h0l, h1h, h1l;
            split_bf(hn0, h0h, h0l);
            split_bf(hn1, h1h, h1l);
            unsigned int dhi = (unsigned)h0h | ((unsigned)h1h << 16);
            unsigned int dlo = (unsigned)h0l | ((unsigned)h1l << 16);
            unsigned int* hw = (unsigned int*)hout;
            // ALWAYS write-through to the coherent point (both paths read it)
            __hip_atomic_store(&hw[nl*132 + u0t*8 + up], dhi,
                               __ATOMIC_RELAXED, __HIP_MEMORY_SCOPE_AGENT);
            __hip_atomic_store(&hw[4224 + nl*132 + u0t*8 + up], dlo,
                               __ATOMIC_RELAXED, __HIP_MEMORY_SCOPE_AGENT);
        }

        if (t < 127) {
            group_barrier(mycnt + t, 16, tid);
#pragma unroll
            for (int g = 0; g < 4; g++) gp[g] = gpn[g];
        }
    }

    // ---- fused pool normalization: emb = sum(h*m)/max(cnt,1) ----
    int cntN = 0;
#pragma unroll 1
    for (int te2 = 0; te2 < 128; ++te2) cntN += mk_lds[nl*128 + te2];
    float inv = 1.0f / fmaxf((float)cntN, 1.0f);
    *(float2*)&pooled[n*512 + dir*256 + ug0] = make_float2(p0*inv, p1*inv);
}

// ---------------------------------------------------------------------------
// FALLBACK ONLY: original per-step word kernel.
__global__ __launch_bounds__(256) void word_step_mfma(
    const float* __restrict__ Gf, const float* __restrict__ Gb,
    const unsigned short* __restrict__ Wimg,
    const unsigned short* __restrict__ hin_img,
    unsigned short* __restrict__ hout_img,
    const int* __restrict__ mask,
    float* __restrict__ c_st, float* __restrict__ pooled, int t)
{
    extern __shared__ char ldsbuf[];
    unsigned short* Wl = (unsigned short*)ldsbuf;
    unsigned short* Hl = Wl + 34816;
    float* gex = (float*)(ldsbuf + 69632 + 36864);

    const int tid = threadIdx.x;
    const int bid = blockIdx.x;
    const int dir = bid >> 7;
    const int u0t = (bid >> 3) & 15;
    const int nt  = bid & 7;
    const int te  = dir ? (127 - t) : t;
    const float* G = dir ? Gb : Gf;

    const int wv = tid >> 6, ln = tid & 63;
    const int c = ln & 15, q = ln >> 4;

    {
        const char* wsrc = (const char*)(Wimg + (size_t)(dir*16 + u0t) * 34816);
        const char* hsrc = (const char*)(hin_img + (size_t)(dir*8 + nt) * 18432);
        char* wdst = (char*)Wl;
        char* hdst = (char*)Hl;
#pragma unroll
        for (int j = 0; j < 17; j++) {
            int i = wv + 4*j;
            __builtin_amdgcn_global_load_lds(
                (const __attribute__((address_space(1))) unsigned int*)(wsrc + i*1024 + ln*16),
                (__attribute__((address_space(3))) unsigned int*)(wdst + i*1024), 16, 0, 0);
        }
#pragma unroll
        for (int j = 0; j < 9; j++) {
            int i = wv + 4*j;
            __builtin_amdgcn_global_load_lds(
                (const __attribute__((address_space(1))) unsigned int*)(hsrc + i*1024 + ln*16),
                (__attribute__((address_space(3))) unsigned int*)(hdst + i*1024), 16, 0, 0);
        }
    }

    const int uu = tid & 15;
    const int np = tid >> 4;
    const int uglob = u0t*16 + uu;
    const int n_a = nt*32 + np*2;
    float gpre[8]; int mk0, mk1; float cold0, cold1, pold0, pold1;
    {
        const float* Ga = G + (size_t)(te*256 + n_a)*1024 + uglob;
        const float* Gc = Ga + 1024;
#pragma unroll
        for (int g = 0; g < 4; g++) { gpre[g] = Ga[g*256]; gpre[4+g] = Gc[g*256]; }
        mk0 = mask[n_a*128 + te];
        mk1 = mask[(n_a + 1)*128 + te];
        cold0 = c_st[dir*65536 + n_a*256 + uglob];
        cold1 = c_st[dir*65536 + (n_a + 1)*256 + uglob];
        pold0 = pooled[n_a*512 + dir*256 + uglob];
        pold1 = pooled[(n_a + 1)*512 + dir*256 + uglob];
    }
    __syncthreads();

    f32x4 acc[2];
    acc[0] = f32x4{0.f,0.f,0.f,0.f};
    acc[1] = f32x4{0.f,0.f,0.f,0.f};
#pragma unroll
    for (int kb = 0; kb < 8; kb++) {
        bf16x8 ahh = *(const bf16x8*)&Wl[(wv*16 + c)*264 + kb*32 + q*8];
        bf16x8 all_ = *(const bf16x8*)&Wl[16896 + (wv*16 + c)*264 + kb*32 + q*8];
#pragma unroll
        for (int sb = 0; sb < 2; sb++) {
            bf16x8 bh = *(const bf16x8*)&Hl[(sb*16 + c)*264 + kb*32 + q*8];
            bf16x8 bl = *(const bf16x8*)&Hl[8448 + (sb*16 + c)*264 + kb*32 + q*8];
            acc[sb] = __builtin_amdgcn_mfma_f32_16x16x32_bf16(ahh, bh, acc[sb], 0, 0, 0);
            acc[sb] = __builtin_amdgcn_mfma_f32_16x16x32_bf16(ahh, bl, acc[sb], 0, 0, 0);
            acc[sb] = __builtin_amdgcn_mfma_f32_16x16x32_bf16(all_, bh, acc[sb], 0, 0, 0);
        }
    }
#pragma unroll
    for (int sb = 0; sb < 2; sb++)
#pragma unroll
        for (int reg = 0; reg < 4; reg++)
            gex[(wv*16 + q*4 + reg)*36 + sb*16 + c] = acc[sb][reg];
    __syncthreads();

    unsigned short* hout = hout_img + (size_t)(dir*8 + nt) * 18432;
    {
        int nl = np*2;
        float iv = gex[(0*16 + uu)*36 + nl] + gpre[0];
        float fv = gex[(1*16 + uu)*36 + nl] + gpre[1];
        float gv = gex[(2*16 + uu)*36 + nl] + gpre[2];
        float ov = gex[(3*16 + uu)*36 + nl] + gpre[3];
        float cn = sigmoidf_(fv)*cold0 + sigmoidf_(iv)*tanhf(gv);
        float hn = sigmoidf_(ov)*tanhf(cn);
        c_st[dir*65536 + n_a*256 + uglob] = cn;
        unsigned short hh, hl; split_bf(hn, hh, hl);
        hout[nl*264 + uglob] = hh;
        hout[8448 + nl*264 + uglob] = hl;
        if (mk0) pooled[n_a*512 + dir*256 + uglob] = pold0 + hn;
    }
    {
        int nl = np*2 + 1;
        float iv = gex[(0*16 + uu)*36 + nl] + gpre[4];
        float fv = gex[(1*16 + uu)*36 + nl] + gpre[5];
        float gv = gex[(2*16 + uu)*36 + nl] + gpre[6];
        float ov = gex[(3*16 + uu)*36 + nl] + gpre[7];
        float cn = sigmoidf_(fv)*cold1 + sigmoidf_(iv)*tanhf(gv);
        float hn = sigmoidf_(ov)*tanhf(cn);
        c_st[dir*65536 + (n_a+1)*256 + uglob] = cn;
        unsigned short hh, hl; split_bf(hn, hh, hl);
        hout[nl*264 + uglob] = hh;
        hout[8448 + nl*264 + uglob] = hl;
        if (mk1) pooled[(n_a+1)*512 + dir*256 + uglob] = pold1 + hn;
    }
}

// ---------------------------------------------------------------------------
// fp32 input-projection GEMM (sentence level), unchanged.
__global__ __launch_bounds__(256) void gemm_proj(
    const float* __restrict__ A, int M, int K,
    const float* __restrict__ Wf, const float* __restrict__ Wb,
    const float* __restrict__ bf, const float* __restrict__ bb,
    float* __restrict__ Of, float* __restrict__ Ob)
{
    __shared__ float As[16][132];
    __shared__ float Bs[16][132];
    const int t = threadIdx.x;
    const int n0 = blockIdx.x * 128;
    const int m0 = blockIdx.y * 128;
    const int sel = (n0 >= 1024);
    const float* Wp = sel ? Wb : Wf;
    const float* bp = sel ? bb : bf;
    float* Op = sel ? Ob : Of;
    const int n0d = n0 & 1023;
    const int tm = t >> 4;
    const int tn = t & 15;

    float acc[8][8];
#pragma unroll
    for (int i = 0; i < 8; i++)
#pragma unroll
        for (int j = 0; j < 8; j++) acc[i][j] = 0.f;

    for (int k0 = 0; k0 < K; k0 += 16) {
        __syncthreads();
#pragma unroll
        for (int rr = 0; rr < 2; rr++) {
            int idx = t + rr * 256;
            int row = idx >> 2, kq = idx & 3;
            float4 v = *(const float4*)&A[(size_t)(m0 + row) * K + k0 + kq * 4];
            As[kq*4+0][row] = v.x; As[kq*4+1][row] = v.y;
            As[kq*4+2][row] = v.z; As[kq*4+3][row] = v.w;
        }
#pragma unroll
        for (int rr = 0; rr < 2; rr++) {
            int idx = t + rr * 256;
            int row = idx >> 2, kq = idx & 3;
            float4 v = *(const float4*)&Wp[(size_t)(n0d + row) * K + k0 + kq * 4];
            Bs[kq*4+0][row] = v.x; Bs[kq*4+1][row] = v.y;
            Bs[kq*4+2][row] = v.z; Bs[kq*4+3][row] = v.w;
        }
        __syncthreads();
#pragma unroll
        for (int k = 0; k < 16; k++) {
            float4 a0 = *(const float4*)&As[k][tm*4];
            float4 a1 = *(const float4*)&As[k][tm*4+64];
            float4 b0 = *(const float4*)&Bs[k][tn*4];
            float4 b1 = *(const float4*)&Bs[k][tn*4+64];
            float av[8] = {a0.x,a0.y,a0.z,a0.w,a1.x,a1.y,a1.z,a1.w};
            float bv[8] = {b0.x,b0.y,b0.z,b0.w,b1.x,b1.y,b1.z,b1.w};
#pragma unroll
            for (int i = 0; i < 8; i++)
#pragma unroll
                for (int j = 0; j < 8; j++)
                    acc[i][j] += av[i] * bv[j];
        }
    }

#pragma unroll
    for (int ih = 0; ih < 2; ih++) {
#pragma unroll
        for (int i = 0; i < 4; i++) {
            int m = m0 + ih*64 + tm*4 + i;
#pragma unroll
            for (int jh = 0; jh < 2; jh++) {
                int col = n0d + jh*64 + tn*4;
                float4 bias4 = *(const float4*)&bp[col];
                float4 r;
                r.x = acc[ih*4+i][jh*4+0] + bias4.x;
                r.y = acc[ih*4+i][jh*4+1] + bias4.y;
                r.z = acc[ih*4+i][jh*4+2] + bias4.z;
                r.w = acc[ih*4+i][jh*4+3] + bias4.w;
                *(float4*)&Op[(size_t)m * 1024 + col] = r;
            }
        }
    }
}

// ---------------------------------------------------------------------------
// FALLBACK ONLY (word fallback path): divide pooled by mask count.
__global__ __launch_bounds__(256) void pool_div(float* __restrict__ pooled,
                                                const int* __restrict__ mask) {
    __shared__ float red[256];
    int n = blockIdx.x, t = threadIdx.x;
    red[t] = (t < 128) ? (float)mask[n*128 + t] : 0.f;
    __syncthreads();
    for (int off = 128; off > 0; off >>= 1) {
        if (t < off) red[t] += red[t + off];
        __syncthreads();
    }
    float inv = 1.0f / fmaxf(red[0], 1.0f);
    pooled[n*512 + t] *= inv;
    pooled[n*512 + 256 + t] *= inv;
}

// ---------------------------------------------------------------------------
// Per-step sentence kernel (launch-loop main path).
__global__ __launch_bounds__(256) void sent_step(
    const float* __restrict__ Gsf, const float* __restrict__ Gsb,
    const float* __restrict__ Wt,
    const float* __restrict__ h_in, float* __restrict__ h_out,
    float* __restrict__ c_s, float* __restrict__ final_h, int s)
{
    __shared__ float h_lds[256];
    __shared__ float part[256];
    __shared__ float ex[4][33];
    const int tid = threadIdx.x;
    const int bx = blockIdx.x;
    const int dir = bx >> 6;
    const int rb = bx & 63;
    const int b = rb >> 3;
    const int ut = rb & 7;
    const int u0 = ut * 32;
    const int t_eff = dir ? (31 - s) : s;
    const float* Gs = dir ? Gsb : Gsf;

    if (tid < 64) {
        float4 v = *(const float4*)&h_in[dir*2048 + b*256 + tid*4];
        *(float4*)&h_lds[tid*4] = v;
    }
    __syncthreads();

    const int kh = tid >> 7;
    const int rr = tid & 127;
    const int g = rr >> 5;
    const int uu = rr & 31;
    const int j = g*256 + u0 + uu;
    const float* wp = Wt + dir*262144 + kh*128*1024 + j;
    float acc = 0.f;
#pragma unroll 8
    for (int k = 0; k < 128; k++)
        acc += wp[k*1024] * h_lds[kh*128 + k];
    part[tid] = acc;
    __syncthreads();
    if (tid < 128) ex[g][uu] = part[tid] + part[tid + 128];
    __syncthreads();

    if (tid < 32) {
        int u = u0 + tid;
        size_t gb = (size_t)(b*32 + t_eff)*1024 + u;
        float iv = ex[0][tid] + Gs[gb];
        float fv = ex[1][tid] + Gs[gb + 256];
        float gv = ex[2][tid] + Gs[gb + 512];
        float ov = ex[3][tid] + Gs[gb + 768];
        int ci = dir*2048 + b*256 + u;
        float cold = c_s[ci];
        float cn = sigmoidf_(fv)*cold + sigmoidf_(iv)*tanhf(gv);
        float hn = sigmoidf_(ov)*tanhf(cn);
        c_s[ci] = cn;
        h_out[ci] = hn;
        if (t_eff == 31) final_h[b*512 + dir*256 + u] = hn;
    }
}

// ---------------------------------------------------------------------------
__global__ __launch_bounds__(256) void logits_k(const float* __restrict__ fh,
                                                const float* __restrict__ cw,
                                                const float* __restrict__ cb,
                                                float* __restrict__ out) {
    __shared__ float red[256];
    int tid = threadIdx.x;
    int o = tid >> 3;
    int b = o >> 2; int c = o & 3;
    int pp = tid & 7;
    float acc = 0.f;
    const float* fv = fh + b*512 + pp*64;
    const float* wv = cw + c*512 + pp*64;
#pragma unroll 8
    for (int e = 0; e < 64; e++) acc += fv[e]*wv[e];
    red[tid] = acc;
    __syncthreads();
    if (pp == 0) {
        float s = 0.f;
#pragma unroll
        for (int qq = 0; qq < 8; qq++) s += red[o*8 + qq];
        out[o] = s + cb[c];
    }
}

// ---------------------------------------------------------------------------
extern "C" void kernel_launch(void* const* d_in, const int* in_sizes, int n_in,
                              void* d_out, int out_size, void* d_ws, size_t ws_size,
                              hipStream_t stream) {
    const float* X       = (const float*)d_in[0];
    const int*   mask    = (const int*)d_in[1];
    const float* wl_ih_f = (const float*)d_in[2];
    const float* wl_hh_f = (const float*)d_in[3];
    const float* wl_b_f  = (const float*)d_in[4];
    const float* wl_ih_b = (const float*)d_in[5];
    const float* wl_hh_b = (const float*)d_in[6];
    const float* wl_b_b  = (const float*)d_in[7];
    const float* ws_ih_f = (const float*)d_in[8];
    const float* ws_hh_f = (const float*)d_in[9];
    const float* ws_b_f  = (const float*)d_in[10];
    const float* ws_ih_b = (const float*)d_in[11];
    const float* ws_hh_b = (const float*)d_in[12];
    const float* ws_b_b  = (const float*)d_in[13];
    const float* cls_w   = (const float*)d_in[14];
    const float* cls_b   = (const float*)d_in[15];
    float* out = (float*)d_out;
    float* w = (float*)d_ws;
    (void)in_sizes; (void)n_in; (void)out_size; (void)ws_size;

    // workspace layout (float offsets)
    float* Gf     = w;                         // 33,554,432 (t-major [t][n][1024])
    float* Gb     = Gf + 33554432;             // 33,554,432
    float* Gsf    = Gb + 33554432;             // 262,144
    float* Gsb    = Gsf + 262144;              // 262,144
    float* Wt     = Gsb + 262144;              // 524,288 (sentence W^T; start of
                                               //   region aliases word counters /
                                               //   self-test buffers — transpose
                                               //   runs AFTER word_recur completes)
    int*   cnt_w  = (int*)Wt;                  // 2176 ints (16 grp x 136 slots)
    int*   cnt_s  = cnt_w + 2176;              // 640 ints  (unused; kept for layout)
    int*   pf     = cnt_s + 640;               // 256 ints  (per-block pass/fail)
    unsigned int* tstg = (unsigned int*)(pf + 256);  // 65536 ints (self-test)
    float* finalh = Wt + 524288;               // 4,096
    // ---- zero region (contiguous) ----
    float* pooled = finalh + 4096;             // 131,072
    float* c_st   = pooled + 131072;           // 131,072 (word fallback only)
    float* hs0    = c_st + 131072;             // 4,096
    float* hs1    = hs0 + 4096;                // 4,096
    float* cs     = hs1 + 4096;                // 4,096 (sentence c-state)
    unsigned short* hA = (unsigned short*)(cs + 4096);  // 294,912 ushorts
    unsigned short* hB = hA + 294912;                   // 294,912
    unsigned short* Xsw   = hB + 294912;                // 50,331,648 ushorts
    unsigned short* Wihsw = Xsw + 50331648;             // 3,145,728
    unsigned short* Wimg  = Wihsw + 3145728;            // 1,114,112

    zero_f4<<<412, 256, 0, stream>>>((float4*)pooled, 105472);
    // counters: 2176 + 640 = 2816 ints = 704 float4
    zero_f4<<<3, 256, 0, stream>>>((float4*)cnt_w, 704);
    prep_x<<<12288, 256, 0, stream>>>(X, Xsw);
    prep_wih_sw<<<768, 256, 0, stream>>>(wl_ih_f, wl_ih_b, Wihsw);
    prep_whh<<<2048, 256, 0, stream>>>(wl_hh_f, wl_hh_b, Wimg);

    // word input projection (split-bf16 MFMA, natural mapping, t-major out)
    proj_mfma<<<dim3(16, 128), 256, 0, stream>>>(Xsw, Wihsw, wl_b_f, wl_b_b, Gf, Gb);

    // ---- word recurrence: ONE persistent kernel (plain launch) ----
    {
        (void)hipGetLastError();   // clear
        word_recur<<<256, 256, 62464, stream>>>(Gf, Gb, Wimg, hA, hB, mask,
                                                pooled, cnt_w, pf, tstg);
        hipError_t e = hipGetLastError();
        if (e != hipSuccess) {
            // fallback: original 128-launch loop + pool_div
            hipFuncSetAttribute((const void*)word_step_mfma,
                                hipFuncAttributeMaxDynamicSharedMemorySize, 115712);
            for (int t = 0; t < 128; t++) {
                const unsigned short* hin = (t & 1) ? hB : hA;
                unsigned short* hout      = (t & 1) ? hA : hB;
                word_step_mfma<<<256, 256, 115712, stream>>>(Gf, Gb, Wimg, hin, hout,
                                                             mask, c_st, pooled, t);
            }
            pool_div<<<256, 256, 0, stream>>>(pooled, mask);
        }
    }

    // sentence W^T (safe: Wt region's aliased counters are dead after word)
    transpose_whh<<<2048, 256, 0, stream>>>(ws_hh_f, ws_hh_b, Wt);

    // sentence input projection (fp32): (256x512) @ (512x2048)
    gemm_proj<<<dim3(16, 2), 256, 0, stream>>>(pooled, 256, 512,
                                               ws_ih_f, ws_ih_b, ws_b_f, ws_b_b,
                                               Gsf, Gsb);

    // ---- sentence recurrence: per-step launch loop ----
    for (int s = 0; s < 32; s++) {
        float* hin  = (s & 1) ? hs1 : hs0;
        float* hout = (s & 1) ? hs0 : hs1;
        sent_step<<<128, 256, 0, stream>>>(Gsf, Gsb, Wt, hin, hout, cs, finalh, s);
    }

    logits_k<<<1, 256, 0, stream>>>(finalh, cls_w, cls_b, out);
}

// Round 10
// 943.517 us; speedup vs baseline: 1.1231x; 1.1231x over previous
//
#include <hip/hip_runtime.h>
#include <math.h>

// Dims: B=8, NS=32, L=128, H=768, LH=256, C=4. N_SEQ=256, gates=1024.

typedef __bf16 bf16x8 __attribute__((ext_vector_type(8)));
typedef float  f32x4  __attribute__((ext_vector_type(4)));

__device__ __forceinline__ float sigmoidf_(float x){ return 1.0f/(1.0f+expf(-x)); }
__device__ __forceinline__ unsigned short f2bf(float x){
    unsigned int b = __float_as_uint(x);
    b += 0x7FFFu + ((b>>16)&1u);
    return (unsigned short)(b>>16);
}
__device__ __forceinline__ float bf2f(unsigned short h){
    return __uint_as_float(((unsigned int)h)<<16);
}
__device__ __forceinline__ void split_bf(float x, unsigned short &hi, unsigned short &lo){
    hi = f2bf(x);
    lo = f2bf(x - bf2f(hi));
}
__device__ __forceinline__ uint4 pack8(const unsigned short* s){
    uint4 u;
    u.x = (unsigned)s[0] | ((unsigned)s[1]<<16);
    u.y = (unsigned)s[2] | ((unsigned)s[3]<<16);
    u.z = (unsigned)s[4] | ((unsigned)s[5]<<16);
    u.w = (unsigned)s[6] | ((unsigned)s[7]<<16);
    return u;
}

// ---------------------------------------------------------------------------
// Counter-based AGENT-scope group barrier — empirically the fastest variant
// (r5/r7: 3.15us/step word incl. stage+compute; r6's epoch-flag was slower).
__device__ __forceinline__ void group_barrier(int* p, int members, int tid) {
    __syncthreads();   // drains vmcnt(0): all threads' stores complete
    if (tid == 0) {
        __hip_atomic_fetch_add(p, 1, __ATOMIC_RELAXED, __HIP_MEMORY_SCOPE_AGENT);
        int it = 0;
        while (__hip_atomic_load(p, __ATOMIC_RELAXED, __HIP_MEMORY_SCOPE_AGENT) < members) {
            __builtin_amdgcn_s_sleep(1);
            if (++it > (1<<22)) break;   // safety: degrade, don't hang
        }
    }
    __builtin_amdgcn_fence(__ATOMIC_ACQUIRE, "workgroup");  // compile-order only
    __syncthreads();
}

// self-test pattern: round 1 is the bitwise inverse of round 0, so a stale
// read (L1, foreign L2, or previous launch) can never match both rounds.
__device__ __forceinline__ unsigned tpat(int bid, int tid, int r) {
    unsigned v = (unsigned)bid * 1315423911u ^ (unsigned)tid * 2654435761u ^ 0x9E3779B9u;
    return r ? ~v : v;
}

// ---------------------------------------------------------------------------
__global__ void zero_f4(float4* __restrict__ p, int n) {
    int i = blockIdx.x * 256 + threadIdx.x;
    if (i < n) p[i] = make_float4(0.f, 0.f, 0.f, 0.f);
}

// ---------------------------------------------------------------------------
// X (32768x768 fp32) -> hi/lo bf16 frag-swizzled blocks.
__global__ void prep_x(const float* __restrict__ X, unsigned short* __restrict__ Xsw) {
    int idx = blockIdx.x * 256 + threadIdx.x;
    int gblk = idx >> 6, ln = idx & 63;
    int mt = gblk / 24, kb = gblk - mt * 24;
    int m = mt * 16 + (ln & 15);
    int k = kb * 32 + (ln >> 4) * 8;
    const float* xp = X + (size_t)m * 768 + k;
    unsigned short hi[8], lo[8];
#pragma unroll
    for (int e = 0; e < 8; e += 4) {
        float4 v = *(const float4*)(xp + e);
        split_bf(v.x, hi[e+0], lo[e+0]);
        split_bf(v.y, hi[e+1], lo[e+1]);
        split_bf(v.z, hi[e+2], lo[e+2]);
        split_bf(v.w, hi[e+3], lo[e+3]);
    }
    *(uint4*)&Xsw[(size_t)gblk*1024 + ln*8]       = pack8(hi);
    *(uint4*)&Xsw[(size_t)gblk*1024 + 512 + ln*8] = pack8(lo);
}

// ---------------------------------------------------------------------------
__global__ void prep_wih_sw(const float* __restrict__ Wf, const float* __restrict__ Wb,
                            unsigned short* __restrict__ Wsw) {
    int idx = blockIdx.x * 256 + threadIdx.x;
    int gblk = idx >> 6, ln = idx & 63;
    int dir = gblk / 1536;
    int rem = gblk - dir * 1536;
    int ntile = rem / 24, kb = rem - ntile * 24;
    int j = ntile * 16 + (ln & 15);
    int k = kb * 32 + (ln >> 4) * 8;
    const float* wp = (dir ? Wb : Wf) + (size_t)j * 768 + k;
    unsigned short hi[8], lo[8];
#pragma unroll
    for (int e = 0; e < 8; e += 4) {
        float4 v = *(const float4*)(wp + e);
        split_bf(v.x, hi[e+0], lo[e+0]);
        split_bf(v.y, hi[e+1], lo[e+1]);
        split_bf(v.z, hi[e+2], lo[e+2]);
        split_bf(v.w, hi[e+3], lo[e+3]);
    }
    *(uint4*)&Wsw[(size_t)gblk*1024 + ln*8]       = pack8(hi);
    *(uint4*)&Wsw[(size_t)gblk*1024 + 512 + ln*8] = pack8(lo);
}

// ---------------------------------------------------------------------------
// Word W_hh images: per (dir, u0t): [hi: 4g x 16u x 264][lo: same].
__global__ void prep_whh(const float* __restrict__ Wf, const float* __restrict__ Wb,
                         unsigned short* __restrict__ Wimg) {
    int idx = blockIdx.x * 256 + threadIdx.x;
    if (idx >= 524288) return;
    int dir = idx >> 18;
    int r   = idx & 262143;
    int u0t = r >> 14;
    int g   = (r >> 12) & 3;
    int u   = (r >> 8) & 15;
    int k   = r & 255;
    const float* W = dir ? Wb : Wf;
    float v = W[(size_t)(g*256 + u0t*16 + u) * 256 + k];
    unsigned short hi, lo; split_bf(v, hi, lo);
    size_t base = (size_t)(dir*16 + u0t) * 34816;
    Wimg[base + (g*16 + u)*264 + k]         = hi;
    Wimg[base + 16896 + (g*16 + u)*264 + k] = lo;
}

// ---------------------------------------------------------------------------
// FALLBACK ONLY: transpose sentence-level W_hh -> Wt[dir][k][j]
__global__ void transpose_whh(const float* __restrict__ Wf, const float* __restrict__ Wb,
                              float* __restrict__ Wt) {
    int idx = blockIdx.x * 256 + threadIdx.x;
    if (idx >= 524288) return;
    int dir = idx >> 18;
    int rem = idx & 262143;
    int k = rem >> 10;
    int j = rem & 1023;
    const float* Wp = dir ? Wb : Wf;
    Wt[idx] = Wp[j * 256 + k];
}

// ---------------------------------------------------------------------------
// Word input projection: split-bf16 MFMA, t-major epilogue, XCD-band block
// remap (r8-vs-r9 A/B measured it ~15us faster than the natural mapping;
// pure bijection, correctness mapping-independent).
__global__ __launch_bounds__(256, 2) void proj_mfma(
    const unsigned short* __restrict__ Xsw,
    const unsigned short* __restrict__ Wihsw,
    const float* __restrict__ bfw, const float* __restrict__ bbw,
    float* __restrict__ Of, float* __restrict__ Ob)
{
    __shared__ unsigned short lds[24576];
    const int tid = threadIdx.x;
    const int d   = blockIdx.x + (blockIdx.y << 4);   // 0..2047 linear id
    const int mt  = ((d & 7) << 4) | ((d >> 7) & 15); // XCD band of 16 mt
    const int nt16 = (d >> 3) & 15;
    const int sel = nt16 >> 3;
    const int ntl = nt16 & 7;
    const float* bias = sel ? bbw : bfw;
    float* Op = sel ? Ob : Of;
    const int wv = tid >> 6, ln = tid & 63;
    const int c = ln & 15, q = ln >> 4;

    f32x4 acc[4][8];
#pragma unroll
    for (int i = 0; i < 4; i++)
#pragma unroll
        for (int j = 0; j < 8; j++) acc[i][j] = f32x4{0.f,0.f,0.f,0.f};

    const unsigned short* Abase = Xsw + (size_t)(mt*16) * 24 * 1024;
    const unsigned short* Bbase = Wihsw + (size_t)(sel*64 + ntl*8) * 24 * 1024;

#pragma unroll 1
    for (int kb = 0; kb < 24; kb++) {
        __syncthreads();
#pragma unroll
        for (int jj = 0; jj < 12; jj++) {
            int cc = wv + 4*jj;
            int isB = (cc >= 32);
            int blk = isB ? ((cc - 32) >> 1) : (cc >> 1);
            int half = cc & 1;
            const unsigned short* src = (isB ? Bbase : Abase)
                                        + (size_t)(blk*24 + kb)*1024 + half*512 + ln*8;
            unsigned short* dst = lds + (isB ? 16384 : 0) + blk*1024 + half*512 + ln*8;
            __builtin_amdgcn_global_load_lds(
                (const __attribute__((address_space(1))) unsigned int*)src,
                (__attribute__((address_space(3))) unsigned int*)dst, 16, 0, 0);
        }
        __syncthreads();

        bf16x8 bhv[8], blv[8];
#pragma unroll
        for (int cb = 0; cb < 8; cb++) {
            bhv[cb] = *(const bf16x8*)&lds[16384 + cb*1024 + ln*8];
            blv[cb] = *(const bf16x8*)&lds[16384 + cb*1024 + 512 + ln*8];
        }
#pragma unroll
        for (int rb = 0; rb < 4; rb++) {
            int it = wv*4 + rb;
            bf16x8 ah = *(const bf16x8*)&lds[it*1024 + ln*8];
            bf16x8 al = *(const bf16x8*)&lds[it*1024 + 512 + ln*8];
#pragma unroll
            for (int cb = 0; cb < 8; cb++) {
                acc[rb][cb] = __builtin_amdgcn_mfma_f32_16x16x32_bf16(ah, bhv[cb], acc[rb][cb], 0,0,0);
                acc[rb][cb] = __builtin_amdgcn_mfma_f32_16x16x32_bf16(ah, blv[cb], acc[rb][cb], 0,0,0);
                acc[rb][cb] = __builtin_amdgcn_mfma_f32_16x16x32_bf16(al, bhv[cb], acc[rb][cb], 0,0,0);
            }
        }
    }

#pragma unroll
    for (int rb = 0; rb < 4; rb++) {
        int mbase = mt*256 + (wv*4 + rb)*16 + q*4;
#pragma unroll
        for (int cb = 0; cb < 8; cb++) {
            int j = ntl*128 + cb*16 + c;
            float bv = bias[j];
#pragma unroll
            for (int reg = 0; reg < 4; reg++) {
                int m = mbase + reg;
                int tt = m & 127, nn = m >> 7;
                Op[(size_t)(tt*256 + nn)*1024 + j] = acc[rb][cb][reg] + bv;
            }
        }
    }
}

// ---------------------------------------------------------------------------
// PERSISTENT word recurrence (r7 config: 400us measured). PLAIN launch;
// per-step sync = counter barrier; producers agent atomic stores; consumer
// fast path = global_load_lds aux=0x11 (L1+L2 bypass, reads L3), self-tested
// at startup; fallback = 8B agent atomics. Pool norm fused.
__global__ __launch_bounds__(256, 1) void word_recur(
    const float* __restrict__ Gf, const float* __restrict__ Gb,
    const unsigned short* __restrict__ Wimg,
    unsigned short* __restrict__ hA, unsigned short* __restrict__ hB,
    const int* __restrict__ mask,
    float* __restrict__ pooled, int* __restrict__ cnt,
    int* __restrict__ pf, unsigned int* __restrict__ tstg)
{
    extern __shared__ char ldsbuf[];
    unsigned short* Hl = (unsigned short*)ldsbuf;            // 36864 B
    float* gex   = (float*)(ldsbuf + 36864);                 // 9216 B  [4][16][36]
    int*   mk_lds= (int*)(ldsbuf + 46080);                   // 16384 B [32 seq][128 t]
    // total 62464 B

    const int tid = threadIdx.x;
    const int bid = blockIdx.x;
    const int dir = (bid >> 3) & 1;
    const int nt  = bid & 7;
    const int u0t = bid >> 4;
    const int grp = bid & 15;
    const float* G = dir ? Gb : Gf;

    const int wv = tid >> 6, ln = tid & 63;
    const int c = ln & 15, q = ln >> 4;

    int* mycnt = cnt + grp * 136;   // slots 0..126 = steps, 127..131 = self-test

    // ---- self-test of the fast consumer path (slots 127..131):
    //      agent atomic store -> agent barrier -> load_lds aux=0x11 ----
    bool fast;
    {
        unsigned* tl = (unsigned*)ldsbuf;         // [4][256] staged partner data
        int* oks = (int*)(ldsbuf + 4096);         // [256]
        int okl = 1;
#pragma unroll 1
        for (int r = 0; r < 2; r++) {
            __hip_atomic_store(&tstg[bid*256 + tid], tpat(bid, tid, r),
                               __ATOMIC_RELAXED, __HIP_MEMORY_SCOPE_AGENT);
            group_barrier(mycnt + 127 + 2*r, 16, tid);          // all wrote
            {
                int pbid = grp + 16*((u0t + 1 + wv) & 15);
                __builtin_amdgcn_global_load_lds(
                    (const __attribute__((address_space(1))) unsigned int*)
                        ((const char*)(tstg + pbid*256) + ln*16),
                    (__attribute__((address_space(3))) unsigned int*)(ldsbuf + wv*1024),
                    16, 0, 0x11 /* SC0|SC1: L1+L2 bypass */);
            }
            __syncthreads();
#pragma unroll
            for (int w2 = 0; w2 < 4; w2++) {
                int pb2 = grp + 16*((u0t + 1 + w2) & 15);
                okl &= (tl[w2*256 + tid] == tpat(pb2, tid, r)) ? 1 : 0;
            }
            group_barrier(mycnt + 128 + 2*r, 16, tid);          // all read
        }
        oks[tid] = okl;
        __syncthreads();
        if (tid == 0) {
            int o = 1;
            for (int i = 0; i < 256; i++) o &= oks[i];
            __hip_atomic_store(&pf[bid], o, __ATOMIC_RELAXED, __HIP_MEMORY_SCOPE_AGENT);
        }
        group_barrier(mycnt + 131, 16, tid);
        int f = 1;
#pragma unroll 1
        for (int k = 0; k < 16; k++)
            f &= __hip_atomic_load(&pf[grp + 16*k],
                                   __ATOMIC_RELAXED, __HIP_MEMORY_SCOPE_AGENT);
        fast = (f != 0);
    }

    // ---- one-time: stage mask rows into LDS ----
    {
        const char* msrc = (const char*)(mask + nt*32*128);
#pragma unroll
        for (int j = 0; j < 4; j++) {
            int i = wv + 4*j;
            __builtin_amdgcn_global_load_lds(
                (const __attribute__((address_space(1))) unsigned int*)(msrc + i*1024 + ln*16),
                (__attribute__((address_space(3))) unsigned int*)(((char*)mk_lds) + i*1024), 16, 0, 0);
        }
    }
    // ---- one-time: W fragments (loop-invariant) ----
    const unsigned short* wbase = Wimg + (size_t)(dir*16 + u0t) * 34816;
    bf16x8 wh_[8], wlo[8];
#pragma unroll
    for (int kb = 0; kb < 8; kb++) {
        wh_[kb] = *(const bf16x8*)&wbase[(wv*16 + c)*264 + kb*32 + q*8];
        wlo[kb] = *(const bf16x8*)&wbase[16896 + (wv*16 + c)*264 + kb*32 + q*8];
    }

    // cell-update mapping: thread owns (seq nl, unit pair up)
    const int nl  = tid >> 3;            // 0..31
    const int up  = tid & 7;             // 0..7 -> units 2*up, 2*up+1
    const int u0  = up*2;
    const int ug0 = u0t*16 + u0;
    const int n   = nt*32 + nl;

    float c0 = 0.f, c1 = 0.f, p0 = 0.f, p1 = 0.f;

    // G prefetch for t = 0
    float2 gp[4];
    {
        const int te0 = dir ? 127 : 0;
        const float* Ga = G + (size_t)(te0*256 + n)*1024 + ug0;
#pragma unroll
        for (int g = 0; g < 4; g++) gp[g] = *(const float2*)&Ga[g*256];
    }

#pragma unroll 1
    for (int t = 0; t < 128; ++t) {
        const int te = dir ? (127 - t) : t;
        const unsigned short* hin = (t & 1) ? hB : hA;
        unsigned short* hout = ((t & 1) ? hA : hB) + (size_t)(dir*8 + nt) * 18432;

        // stage h image (36 KB)
        if (fast) {
            const char* hsrc = (const char*)(hin + (size_t)(dir*8 + nt) * 18432);
#pragma unroll
            for (int j = 0; j < 9; j++) {
                int i = wv + 4*j;
                __builtin_amdgcn_global_load_lds(
                    (const __attribute__((address_space(1))) unsigned int*)(hsrc + i*1024 + ln*16),
                    (__attribute__((address_space(3))) unsigned int*)(ldsbuf + i*1024),
                    16, 0, 0x11 /* SC0|SC1 */);
            }
        } else {
            const unsigned long long* hsrc =
                (const unsigned long long*)(hin + (size_t)(dir*8 + nt) * 18432);
            unsigned long long* hdst = (unsigned long long*)ldsbuf;
#pragma unroll
            for (int j = 0; j < 18; j++) {
                unsigned long long v = __hip_atomic_load(hsrc + tid + 256*j,
                        __ATOMIC_RELAXED, __HIP_MEMORY_SCOPE_AGENT);
                hdst[tid + 256*j] = v;
            }
        }
        __syncthreads();   // staging complete

        f32x4 acc[2];
        acc[0] = f32x4{0.f,0.f,0.f,0.f};
        acc[1] = f32x4{0.f,0.f,0.f,0.f};
#pragma unroll
        for (int kb = 0; kb < 8; kb++) {
#pragma unroll
            for (int sb = 0; sb < 2; sb++) {
                bf16x8 bh = *(const bf16x8*)&Hl[(sb*16 + c)*264 + kb*32 + q*8];
                bf16x8 bl = *(const bf16x8*)&Hl[8448 + (sb*16 + c)*264 + kb*32 + q*8];
                acc[sb] = __builtin_amdgcn_mfma_f32_16x16x32_bf16(wh_[kb], bh, acc[sb], 0, 0, 0);
                acc[sb] = __builtin_amdgcn_mfma_f32_16x16x32_bf16(wh_[kb], bl, acc[sb], 0, 0, 0);
                acc[sb] = __builtin_amdgcn_mfma_f32_16x16x32_bf16(wlo[kb], bh, acc[sb], 0, 0, 0);
            }
        }
#pragma unroll
        for (int sb = 0; sb < 2; sb++)
#pragma unroll
            for (int reg = 0; reg < 4; reg++)
                gex[(wv*16 + q*4 + reg)*36 + sb*16 + c] = acc[sb][reg];
        __syncthreads();

        // G prefetch for t+1: issued here so HBM latency hides under the
        // cell-update transcendentals.
        float2 gpn[4];
        if (t < 127) {
            const int te1 = dir ? (126 - t) : (t + 1);
            const float* Ga = G + (size_t)(te1*256 + n)*1024 + ug0;
#pragma unroll
            for (int g = 0; g < 4; g++) gpn[g] = *(const float2*)&Ga[g*256];
        }

        // ---- cell update: (nl, u0) and (nl, u0+1), state in registers ----
        const int mk = mk_lds[nl*128 + te];
        float iv0 = gex[(0*16 + u0)*36 + nl] + gp[0].x;
        float fv0 = gex[(1*16 + u0)*36 + nl] + gp[1].x;
        float gv0 = gex[(2*16 + u0)*36 + nl] + gp[2].x;
        float ov0 = gex[(3*16 + u0)*36 + nl] + gp[3].x;
        float iv1 = gex[(0*16 + u0+1)*36 + nl] + gp[0].y;
        float fv1 = gex[(1*16 + u0+1)*36 + nl] + gp[1].y;
        float gv1 = gex[(2*16 + u0+1)*36 + nl] + gp[2].y;
        float ov1 = gex[(3*16 + u0+1)*36 + nl] + gp[3].y;
        float cn0 = sigmoidf_(fv0)*c0 + sigmoidf_(iv0)*tanhf(gv0);
        float hn0 = sigmoidf_(ov0)*tanhf(cn0);
        float cn1 = sigmoidf_(fv1)*c1 + sigmoidf_(iv1)*tanhf(gv1);
        float hn1 = sigmoidf_(ov1)*tanhf(cn1);
        c0 = cn0; c1 = cn1;
        if (mk) { p0 += hn0; p1 += hn1; }
        if (t != 127) {
            unsigned short h0h, h0l, h1h, h1l;
            split_bf(hn0, h0h, h0l);
            split_bf(hn1, h1h, h1l);
            unsigned int dhi = (unsigned)h0h | ((unsigned)h1h << 16);
            unsigned int dlo = (unsigned)h0l | ((unsigned)h1l << 16);
            unsigned int* hw = (unsigned int*)hout;
            // ALWAYS write-through to the coherent point (both paths read it)
            __hip_atomic_store(&hw[nl*132 + u0t*8 + up], dhi,
                               __ATOMIC_RELAXED, __HIP_MEMORY_SCOPE_AGENT);
            __hip_atomic_store(&hw[4224 + nl*132 + u0t*8 + up], dlo,
                               __ATOMIC_RELAXED, __HIP_MEMORY_SCOPE_AGENT);
        }

        if (t < 127) {
            group_barrier(mycnt + t, 16, tid);
#pragma unroll
            for (int g = 0; g < 4; g++) gp[g] = gpn[g];
        }
    }

    // ---- fused pool normalization: emb = sum(h*m)/max(cnt,1) ----
    int cntN = 0;
#pragma unroll 1
    for (int te2 = 0; te2 < 128; ++te2) cntN += mk_lds[nl*128 + te2];
    float inv = 1.0f / fmaxf((float)cntN, 1.0f);
    *(float2*)&pooled[n*512 + dir*256 + ug0] = make_float2(p0*inv, p1*inv);
}

// ---------------------------------------------------------------------------
// FALLBACK ONLY: original per-step word kernel.
__global__ __launch_bounds__(256) void word_step_mfma(
    const float* __restrict__ Gf, const float* __restrict__ Gb,
    const unsigned short* __restrict__ Wimg,
    const unsigned short* __restrict__ hin_img,
    unsigned short* __restrict__ hout_img,
    const int* __restrict__ mask,
    float* __restrict__ c_st, float* __restrict__ pooled, int t)
{
    extern __shared__ char ldsbuf[];
    unsigned short* Wl = (unsigned short*)ldsbuf;
    unsigned short* Hl = Wl + 34816;
    float* gex = (float*)(ldsbuf + 69632 + 36864);

    const int tid = threadIdx.x;
    const int bid = blockIdx.x;
    const int dir = bid >> 7;
    const int u0t = (bid >> 3) & 15;
    const int nt  = bid & 7;
    const int te  = dir ? (127 - t) : t;
    const float* G = dir ? Gb : Gf;

    const int wv = tid >> 6, ln = tid & 63;
    const int c = ln & 15, q = ln >> 4;

    {
        const char* wsrc = (const char*)(Wimg + (size_t)(dir*16 + u0t) * 34816);
        const char* hsrc = (const char*)(hin_img + (size_t)(dir*8 + nt) * 18432);
        char* wdst = (char*)Wl;
        char* hdst = (char*)Hl;
#pragma unroll
        for (int j = 0; j < 17; j++) {
            int i = wv + 4*j;
            __builtin_amdgcn_global_load_lds(
                (const __attribute__((address_space(1))) unsigned int*)(wsrc + i*1024 + ln*16),
                (__attribute__((address_space(3))) unsigned int*)(wdst + i*1024), 16, 0, 0);
        }
#pragma unroll
        for (int j = 0; j < 9; j++) {
            int i = wv + 4*j;
            __builtin_amdgcn_global_load_lds(
                (const __attribute__((address_space(1))) unsigned int*)(hsrc + i*1024 + ln*16),
                (__attribute__((address_space(3))) unsigned int*)(hdst + i*1024), 16, 0, 0);
        }
    }

    const int uu = tid & 15;
    const int np = tid >> 4;
    const int uglob = u0t*16 + uu;
    const int n_a = nt*32 + np*2;
    float gpre[8]; int mk0, mk1; float cold0, cold1, pold0, pold1;
    {
        const float* Ga = G + (size_t)(te*256 + n_a)*1024 + uglob;
        const float* Gc = Ga + 1024;
#pragma unroll
        for (int g = 0; g < 4; g++) { gpre[g] = Ga[g*256]; gpre[4+g] = Gc[g*256]; }
        mk0 = mask[n_a*128 + te];
        mk1 = mask[(n_a + 1)*128 + te];
        cold0 = c_st[dir*65536 + n_a*256 + uglob];
        cold1 = c_st[dir*65536 + (n_a + 1)*256 + uglob];
        pold0 = pooled[n_a*512 + dir*256 + uglob];
        pold1 = pooled[(n_a + 1)*512 + dir*256 + uglob];
    }
    __syncthreads();

    f32x4 acc[2];
    acc[0] = f32x4{0.f,0.f,0.f,0.f};
    acc[1] = f32x4{0.f,0.f,0.f,0.f};
#pragma unroll
    for (int kb = 0; kb < 8; kb++) {
        bf16x8 ahh = *(const bf16x8*)&Wl[(wv*16 + c)*264 + kb*32 + q*8];
        bf16x8 all_ = *(const bf16x8*)&Wl[16896 + (wv*16 + c)*264 + kb*32 + q*8];
#pragma unroll
        for (int sb = 0; sb < 2; sb++) {
            bf16x8 bh = *(const bf16x8*)&Hl[(sb*16 + c)*264 + kb*32 + q*8];
            bf16x8 bl = *(const bf16x8*)&Hl[8448 + (sb*16 + c)*264 + kb*32 + q*8];
            acc[sb] = __builtin_amdgcn_mfma_f32_16x16x32_bf16(ahh, bh, acc[sb], 0, 0, 0);
            acc[sb] = __builtin_amdgcn_mfma_f32_16x16x32_bf16(ahh, bl, acc[sb], 0, 0, 0);
            acc[sb] = __builtin_amdgcn_mfma_f32_16x16x32_bf16(all_, bh, acc[sb], 0, 0, 0);
        }
    }
#pragma unroll
    for (int sb = 0; sb < 2; sb++)
#pragma unroll
        for (int reg = 0; reg < 4; reg++)
            gex[(wv*16 + q*4 + reg)*36 + sb*16 + c] = acc[sb][reg];
    __syncthreads();

    unsigned short* hout = hout_img + (size_t)(dir*8 + nt) * 18432;
    {
        int nl = np*2;
        float iv = gex[(0*16 + uu)*36 + nl] + gpre[0];
        float fv = gex[(1*16 + uu)*36 + nl] + gpre[1];
        float gv = gex[(2*16 + uu)*36 + nl] + gpre[2];
        float ov = gex[(3*16 + uu)*36 + nl] + gpre[3];
        float cn = sigmoidf_(fv)*cold0 + sigmoidf_(iv)*tanhf(gv);
        float hn = sigmoidf_(ov)*tanhf(cn);
        c_st[dir*65536 + n_a*256 + uglob] = cn;
        unsigned short hh, hl; split_bf(hn, hh, hl);
        hout[nl*264 + uglob] = hh;
        hout[8448 + nl*264 + uglob] = hl;
        if (mk0) pooled[n_a*512 + dir*256 + uglob] = pold0 + hn;
    }
    {
        int nl = np*2 + 1;
        float iv = gex[(0*16 + uu)*36 + nl] + gpre[4];
        float fv = gex[(1*16 + uu)*36 + nl] + gpre[5];
        float gv = gex[(2*16 + uu)*36 + nl] + gpre[6];
        float ov = gex[(3*16 + uu)*36 + nl] + gpre[7];
        float cn = sigmoidf_(fv)*cold1 + sigmoidf_(iv)*tanhf(gv);
        float hn = sigmoidf_(ov)*tanhf(cn);
        c_st[dir*65536 + (n_a+1)*256 + uglob] = cn;
        unsigned short hh, hl; split_bf(hn, hh, hl);
        hout[nl*264 + uglob] = hh;
        hout[8448 + nl*264 + uglob] = hl;
        if (mk1) pooled[(n_a+1)*512 + dir*256 + uglob] = pold1 + hn;
    }
}

// ---------------------------------------------------------------------------
// fp32 input-projection GEMM (sentence level), unchanged.
__global__ __launch_bounds__(256) void gemm_proj(
    const float* __restrict__ A, int M, int K,
    const float* __restrict__ Wf, const float* __restrict__ Wb,
    const float* __restrict__ bf, const float* __restrict__ bb,
    float* __restrict__ Of, float* __restrict__ Ob)
{
    __shared__ float As[16][132];
    __shared__ float Bs[16][132];
    const int t = threadIdx.x;
    const int n0 = blockIdx.x * 128;
    const int m0 = blockIdx.y * 128;
    const int sel = (n0 >= 1024);
    const float* Wp = sel ? Wb : Wf;
    const float* bp = sel ? bb : bf;
    float* Op = sel ? Ob : Of;
    const int n0d = n0 & 1023;
    const int tm = t >> 4;
    const int tn = t & 15;

    float acc[8][8];
#pragma unroll
    for (int i = 0; i < 8; i++)
#pragma unroll
        for (int j = 0; j < 8; j++) acc[i][j] = 0.f;

    for (int k0 = 0; k0 < K; k0 += 16) {
        __syncthreads();
#pragma unroll
        for (int rr = 0; rr < 2; rr++) {
            int idx = t + rr * 256;
            int row = idx >> 2, kq = idx & 3;
            float4 v = *(const float4*)&A[(size_t)(m0 + row) * K + k0 + kq * 4];
            As[kq*4+0][row] = v.x; As[kq*4+1][row] = v.y;
            As[kq*4+2][row] = v.z; As[kq*4+3][row] = v.w;
        }
#pragma unroll
        for (int rr = 0; rr < 2; rr++) {
            int idx = t + rr * 256;
            int row = idx >> 2, kq = idx & 3;
            float4 v = *(const float4*)&Wp[(size_t)(n0d + row) * K + k0 + kq * 4];
            Bs[kq*4+0][row] = v.x; Bs[kq*4+1][row] = v.y;
            Bs[kq*4+2][row] = v.z; Bs[kq*4+3][row] = v.w;
        }
        __syncthreads();
#pragma unroll
        for (int k = 0; k < 16; k++) {
            float4 a0 = *(const float4*)&As[k][tm*4];
            float4 a1 = *(const float4*)&As[k][tm*4+64];
            float4 b0 = *(const float4*)&Bs[k][tn*4];
            float4 b1 = *(const float4*)&Bs[k][tn*4+64];
            float av[8] = {a0.x,a0.y,a0.z,a0.w,a1.x,a1.y,a1.z,a1.w};
            float bv[8] = {b0.x,b0.y,b0.z,b0.w,b1.x,b1.y,b1.z,b1.w};
#pragma unroll
            for (int i = 0; i < 8; i++)
#pragma unroll
                for (int j = 0; j < 8; j++)
                    acc[i][j] += av[i] * bv[j];
        }
    }

#pragma unroll
    for (int ih = 0; ih < 2; ih++) {
#pragma unroll
        for (int i = 0; i < 4; i++) {
            int m = m0 + ih*64 + tm*4 + i;
#pragma unroll
            for (int jh = 0; jh < 2; jh++) {
                int col = n0d + jh*64 + tn*4;
                float4 bias4 = *(const float4*)&bp[col];
                float4 r;
                r.x = acc[ih*4+i][jh*4+0] + bias4.x;
                r.y = acc[ih*4+i][jh*4+1] + bias4.y;
                r.z = acc[ih*4+i][jh*4+2] + bias4.z;
                r.w = acc[ih*4+i][jh*4+3] + bias4.w;
                *(float4*)&Op[(size_t)m * 1024 + col] = r;
            }
        }
    }
}

// ---------------------------------------------------------------------------
// FALLBACK ONLY (word fallback path): divide pooled by mask count.
__global__ __launch_bounds__(256) void pool_div(float* __restrict__ pooled,
                                                const int* __restrict__ mask) {
    __shared__ float red[256];
    int n = blockIdx.x, t = threadIdx.x;
    red[t] = (t < 128) ? (float)mask[n*128 + t] : 0.f;
    __syncthreads();
    for (int off = 128; off > 0; off >>= 1) {
        if (t < off) red[t] += red[t + off];
        __syncthreads();
    }
    float inv = 1.0f / fmaxf(red[0], 1.0f);
    pooled[n*512 + t] *= inv;
    pooled[n*512 + 256 + t] *= inv;
}

// ---------------------------------------------------------------------------
// PERSISTENT sentence recurrence (r7 config — measured best; the per-step
// launch loop was 100us SLOWER, r9 A/B). Counter per-step barrier; producers
// agent atomic stores; self-tested fast consumer = load_lds aux=0x11;
// fallback = 8B agent atomics. W_hh in LDS; c in regs.
__global__ __launch_bounds__(256) void sent_recur(
    const float* __restrict__ Gsf, const float* __restrict__ Gsb,
    const float* __restrict__ Whf, const float* __restrict__ Whb,
    float* __restrict__ hs0, float* __restrict__ hs1,
    float* __restrict__ final_h, int* __restrict__ cnt,
    int* __restrict__ pf, unsigned int* __restrict__ tstg)
{
    extern __shared__ char sbuf[];
    float* Wlds  = (float*)sbuf;                 // 128 x 260 floats = 133120 B
    float* h_lds = Wlds + 128*260;               // 256
    float* part  = h_lds + 256;                  // 256
    float* ex    = part + 256;                   // 132

    const int tid = threadIdx.x;
    const int bid = blockIdx.x;
    const int dir = (bid >> 3) & 1;
    const int b   = bid & 7;
    const int ut  = bid >> 4;
    const int grp = bid & 15;
    const float* Gs = dir ? Gsb : Gsf;
    const float* Wh = dir ? Whb : Whf;
    const int wv = tid >> 6, ln = tid & 63;

    int* mycnt = cnt + grp * 40;    // slots 0..30 = steps, 31..35 = self-test

    // ---- self-test (slots 31..35), uses Wlds area before W is staged ----
    bool fast;
    {
        unsigned* tl  = (unsigned*)sbuf;          // [4][256]
        int* oks = (int*)(sbuf + 4096);           // [256]
        int okl = 1;
#pragma unroll 1
        for (int r = 0; r < 2; r++) {
            __hip_atomic_store(&tstg[bid*256 + tid], tpat(bid, tid, r) ^ 0x5A5A5A5Au,
                               __ATOMIC_RELAXED, __HIP_MEMORY_SCOPE_AGENT);
            group_barrier(mycnt + 31 + 2*r, 8, tid);
            {
                int pbid = grp + 16*((ut + 1 + wv) & 7);
                __builtin_amdgcn_global_load_lds(
                    (const __attribute__((address_space(1))) unsigned int*)
                        ((const char*)(tstg + pbid*256) + ln*16),
                    (__attribute__((address_space(3))) unsigned int*)(sbuf + wv*1024),
                    16, 0, 0x11 /* SC0|SC1 */);
            }
            __syncthreads();
#pragma unroll
            for (int w2 = 0; w2 < 4; w2++) {
                int pb2 = grp + 16*((ut + 1 + w2) & 7);
                okl &= (tl[w2*256 + tid] == (tpat(pb2, tid, r) ^ 0x5A5A5A5Au)) ? 1 : 0;
            }
            group_barrier(mycnt + 32 + 2*r, 8, tid);
        }
        oks[tid] = okl;
        __syncthreads();
        if (tid == 0) {
            int o = 1;
            for (int i = 0; i < 256; i++) o &= oks[i];
            __hip_atomic_store(&pf[bid], o, __ATOMIC_RELAXED, __HIP_MEMORY_SCOPE_AGENT);
        }
        group_barrier(mycnt + 35, 8, tid);
        int f = 1;
#pragma unroll 1
        for (int k = 0; k < 8; k++)
            f &= __hip_atomic_load(&pf[grp + 16*k],
                                   __ATOMIC_RELAXED, __HIP_MEMORY_SCOPE_AGENT);
        fast = (f != 0);
    }

    // one-time: stage 128 W rows (1 KB each, coalesced)
#pragma unroll
    for (int j = 0; j < 32; j++) {
        int chunk = wv + 4*j;
        int g = chunk >> 5, u2 = chunk & 31;
        const char* src = (const char*)(Wh + (size_t)(g*256 + ut*32 + u2) * 256);
        __builtin_amdgcn_global_load_lds(
            (const __attribute__((address_space(1))) unsigned int*)(src + ln*16),
            (__attribute__((address_space(3))) unsigned int*)((char*)(Wlds + chunk*260)), 16, 0, 0);
    }

    const int jloc = tid & 127, kh = tid >> 7;
    float creg = 0.f;

#pragma unroll 1
    for (int s = 0; s < 32; ++s) {
        const int t_eff = dir ? (31 - s) : s;
        const float* hin = (s & 1) ? hs1 : hs0;
        float* hout = (s & 1) ? hs0 : hs1;

        // stage h (256 floats = 1 KB)
        if (fast) {
            if (wv == 0)
                __builtin_amdgcn_global_load_lds(
                    (const __attribute__((address_space(1))) unsigned int*)
                        ((const char*)(hin + dir*2048 + b*256) + ln*16),
                    (__attribute__((address_space(3))) unsigned int*)((char*)h_lds),
                    16, 0, 0x11 /* SC0|SC1 */);
        } else if (tid < 128) {
            const unsigned long long* hp =
                (const unsigned long long*)(hin + dir*2048 + b*256);
            unsigned long long v = __hip_atomic_load(hp + tid,
                    __ATOMIC_RELAXED, __HIP_MEMORY_SCOPE_AGENT);
            *(unsigned long long*)&h_lds[tid*2] = v;
        }

        float gsv = 0.f;
        if (tid < 128)
            gsv = Gs[(size_t)(b*32 + t_eff)*1024 + (jloc >> 5)*256 + ut*32 + (jloc & 31)];

        __syncthreads();   // W (s=0) + h staged

        const float* wrow = Wlds + jloc*260 + kh*128;
        const float* hrow = h_lds + kh*128;
        float acc = 0.f;
#pragma unroll
        for (int kc = 0; kc < 32; kc++) {
            float4 w4 = *(const float4*)(wrow + kc*4);
            float4 h4 = *(const float4*)(hrow + kc*4);
            acc += w4.x*h4.x + w4.y*h4.y + w4.z*h4.z + w4.w*h4.w;
        }
        part[tid] = acc;
        __syncthreads();
        if (tid < 128)
            ex[(jloc >> 5)*33 + (jloc & 31)] = part[tid] + part[tid + 128] + gsv;
        __syncthreads();
        if (tid < 32) {
            float iv = ex[0*33 + tid];
            float fv = ex[1*33 + tid];
            float gv = ex[2*33 + tid];
            float ov = ex[3*33 + tid];
            float cn = sigmoidf_(fv)*creg + sigmoidf_(iv)*tanhf(gv);
            float hn = sigmoidf_(ov)*tanhf(cn);
            creg = cn;
            int u = ut*32 + tid;
            // ALWAYS write-through to the coherent point
            __hip_atomic_store((unsigned int*)&hout[dir*2048 + b*256 + u],
                               __float_as_uint(hn),
                               __ATOMIC_RELAXED, __HIP_MEMORY_SCOPE_AGENT);
            if (t_eff == 31) final_h[b*512 + dir*256 + u] = hn;
        }
        if (s < 31) group_barrier(mycnt + s, 8, tid);
    }
}

// ---------------------------------------------------------------------------
// FALLBACK ONLY: original per-step sentence kernel.
__global__ __launch_bounds__(256) void sent_step(
    const float* __restrict__ Gsf, const float* __restrict__ Gsb,
    const float* __restrict__ Wt,
    const float* __restrict__ h_in, float* __restrict__ h_out,
    float* __restrict__ c_s, float* __restrict__ final_h, int s)
{
    __shared__ float h_lds[256];
    __shared__ float part[256];
    __shared__ float ex[4][33];
    const int tid = threadIdx.x;
    const int bx = blockIdx.x;
    const int dir = bx >> 6;
    const int rb = bx & 63;
    const int b = rb >> 3;
    const int ut = rb & 7;
    const int u0 = ut * 32;
    const int t_eff = dir ? (31 - s) : s;
    const float* Gs = dir ? Gsb : Gsf;

    if (tid < 64) {
        float4 v = *(const float4*)&h_in[dir*2048 + b*256 + tid*4];
        *(float4*)&h_lds[tid*4] = v;
    }
    __syncthreads();

    const int kh = tid >> 7;
    const int rr = tid & 127;
    const int g = rr >> 5;
    const int uu = rr & 31;
    const int j = g*256 + u0 + uu;
    const float* wp = Wt + dir*262144 + kh*128*1024 + j;
    float acc = 0.f;
#pragma unroll 8
    for (int k = 0; k < 128; k++)
        acc += wp[k*1024] * h_lds[kh*128 + k];
    part[tid] = acc;
    __syncthreads();
    if (tid < 128) ex[g][uu] = part[tid] + part[tid + 128];
    __syncthreads();

    if (tid < 32) {
        int u = u0 + tid;
        size_t gb = (size_t)(b*32 + t_eff)*1024 + u;
        float iv = ex[0][tid] + Gs[gb];
        float fv = ex[1][tid] + Gs[gb + 256];
        float gv = ex[2][tid] + Gs[gb + 512];
        float ov = ex[3][tid] + Gs[gb + 768];
        int ci = dir*2048 + b*256 + u;
        float cold = c_s[ci];
        float cn = sigmoidf_(fv)*cold + sigmoidf_(iv)*tanhf(gv);
        float hn = sigmoidf_(ov)*tanhf(cn);
        c_s[ci] = cn;
        h_out[ci] = hn;
        if (t_eff == 31) final_h[b*512 + dir*256 + u] = hn;
    }
}

// ---------------------------------------------------------------------------
__global__ __launch_bounds__(256) void logits_k(const float* __restrict__ fh,
                                                const float* __restrict__ cw,
                                                const float* __restrict__ cb,
                                                float* __restrict__ out) {
    __shared__ float red[256];
    int tid = threadIdx.x;
    int o = tid >> 3;
    int b = o >> 2; int c = o & 3;
    int pp = tid & 7;
    float acc = 0.f;
    const float* fv = fh + b*512 + pp*64;
    const float* wv = cw + c*512 + pp*64;
#pragma unroll 8
    for (int e = 0; e < 64; e++) acc += fv[e]*wv[e];
    red[tid] = acc;
    __syncthreads();
    if (pp == 0) {
        float s = 0.f;
#pragma unroll
        for (int qq = 0; qq < 8; qq++) s += red[o*8 + qq];
        out[o] = s + cb[c];
    }
}

// ---------------------------------------------------------------------------
extern "C" void kernel_launch(void* const* d_in, const int* in_sizes, int n_in,
                              void* d_out, int out_size, void* d_ws, size_t ws_size,
                              hipStream_t stream) {
    const float* X       = (const float*)d_in[0];
    const int*   mask    = (const int*)d_in[1];
    const float* wl_ih_f = (const float*)d_in[2];
    const float* wl_hh_f = (const float*)d_in[3];
    const float* wl_b_f  = (const float*)d_in[4];
    const float* wl_ih_b = (const float*)d_in[5];
    const float* wl_hh_b = (const float*)d_in[6];
    const float* wl_b_b  = (const float*)d_in[7];
    const float* ws_ih_f = (const float*)d_in[8];
    const float* ws_hh_f = (const float*)d_in[9];
    const float* ws_b_f  = (const float*)d_in[10];
    const float* ws_ih_b = (const float*)d_in[11];
    const float* ws_hh_b = (const float*)d_in[12];
    const float* ws_b_b  = (const float*)d_in[13];
    const float* cls_w   = (const float*)d_in[14];
    const float* cls_b   = (const float*)d_in[15];
    float* out = (float*)d_out;
    float* w = (float*)d_ws;
    (void)in_sizes; (void)n_in; (void)out_size; (void)ws_size;

    // workspace layout (float offsets)
    float* Gf     = w;                         // 33,554,432 (t-major [t][n][1024])
    float* Gb     = Gf + 33554432;             // 33,554,432
    float* Gsf    = Gb + 33554432;             // 262,144
    float* Gsb    = Gsf + 262144;              // 262,144
    float* Wt     = Gsb + 262144;              // 524,288 (fallback W^T; main path
                                               //   aliases counters/test buffers)
    int*   cnt_w  = (int*)Wt;                  // 2176 ints (16 grp x 136 slots)
    int*   cnt_s  = cnt_w + 2176;              // 640 ints  (16 grp x 40 slots)
    int*   pf     = cnt_s + 640;               // 256 ints  (per-block pass/fail)
    unsigned int* tstg = (unsigned int*)(pf + 256);  // 65536 ints (self-test)
    float* finalh = Wt + 524288;               // 4,096
    // ---- zero region (contiguous) ----
    float* pooled = finalh + 4096;             // 131,072
    float* c_st   = pooled + 131072;           // 131,072 (fallback only)
    float* hs0    = c_st + 131072;             // 4,096
    float* hs1    = hs0 + 4096;                // 4,096
    float* cs     = hs1 + 4096;                // 4,096 (fallback only)
    unsigned short* hA = (unsigned short*)(cs + 4096);  // 294,912 ushorts
    unsigned short* hB = hA + 294912;                   // 294,912
    unsigned short* Xsw   = hB + 294912;                // 50,331,648 ushorts
    unsigned short* Wihsw = Xsw + 50331648;             // 3,145,728
    unsigned short* Wimg  = Wihsw + 3145728;            // 1,114,112

    zero_f4<<<412, 256, 0, stream>>>((float4*)pooled, 105472);
    // counters: 2176 + 640 = 2816 ints = 704 float4
    zero_f4<<<3, 256, 0, stream>>>((float4*)cnt_w, 704);
    prep_x<<<12288, 256, 0, stream>>>(X, Xsw);
    prep_wih_sw<<<768, 256, 0, stream>>>(wl_ih_f, wl_ih_b, Wihsw);
    prep_whh<<<2048, 256, 0, stream>>>(wl_hh_f, wl_hh_b, Wimg);

    // word input projection (split-bf16 MFMA, XCD-band swizzle, t-major out)
    proj_mfma<<<dim3(16, 128), 256, 0, stream>>>(Xsw, Wihsw, wl_b_f, wl_b_b, Gf, Gb);

    // ---- word recurrence: ONE persistent kernel (plain launch;
    //      co-residency by capacity: 256 blocks @ 62.5KB LDS) ----
    {
        (void)hipGetLastError();   // clear
        word_recur<<<256, 256, 62464, stream>>>(Gf, Gb, Wimg, hA, hB, mask,
                                                pooled, cnt_w, pf, tstg);
        hipError_t e = hipGetLastError();
        if (e != hipSuccess) {
            // fallback: original 128-launch loop + pool_div
            hipFuncSetAttribute((const void*)word_step_mfma,
                                hipFuncAttributeMaxDynamicSharedMemorySize, 115712);
            for (int t = 0; t < 128; t++) {
                const unsigned short* hin = (t & 1) ? hB : hA;
                unsigned short* hout      = (t & 1) ? hA : hB;
                word_step_mfma<<<256, 256, 115712, stream>>>(Gf, Gb, Wimg, hin, hout,
                                                             mask, c_st, pooled, t);
            }
            pool_div<<<256, 256, 0, stream>>>(pooled, mask);
        }
    }

    // sentence input projection (fp32): (256x512) @ (512x2048)
    gemm_proj<<<dim3(16, 2), 256, 0, stream>>>(pooled, 256, 512,
                                               ws_ih_f, ws_ih_b, ws_b_f, ws_b_b,
                                               Gsf, Gsb);

    // ---- sentence recurrence: ONE persistent kernel (plain launch;
    //      128 blocks @ 133KB LDS) — measured faster than launch loop ----
    {
        hipFuncSetAttribute((const void*)sent_recur,
                            hipFuncAttributeMaxDynamicSharedMemorySize, 135696);
        (void)hipGetLastError();   // clear
        sent_recur<<<128, 256, 135696, stream>>>(Gsf, Gsb, ws_hh_f, ws_hh_b,
                                                 hs0, hs1, finalh, cnt_s,
                                                 pf, tstg);
        hipError_t e = hipGetLastError();
        if (e != hipSuccess) {
            // fallback: transpose + original 32-launch loop
            transpose_whh<<<2048, 256, 0, stream>>>(ws_hh_f, ws_hh_b, Wt);
            for (int s = 0; s < 32; s++) {
                float* hin  = (s & 1) ? hs1 : hs0;
                float* hout = (s & 1) ? hs0 : hs1;
                sent_step<<<128, 256, 0, stream>>>(Gsf, Gsb, Wt, hin, hout, cs, finalh, s);
            }
        }
    }

    logits_k<<<1, 256, 0, stream>>>(finalh, cls_w, cls_b, out);
}

// Round 11
// 934.494 us; speedup vs baseline: 1.1339x; 1.0097x over previous
//
#include <hip/hip_runtime.h>
#include <math.h>

// Dims: B=8, NS=32, L=128, H=768, LH=256, C=4. N_SEQ=256, gates=1024.

typedef __bf16 bf16x8 __attribute__((ext_vector_type(8)));
typedef float  f32x4  __attribute__((ext_vector_type(4)));

__device__ __forceinline__ float sigmoidf_(float x){ return 1.0f/(1.0f+expf(-x)); }
__device__ __forceinline__ unsigned short f2bf(float x){
    unsigned int b = __float_as_uint(x);
    b += 0x7FFFu + ((b>>16)&1u);
    return (unsigned short)(b>>16);
}
__device__ __forceinline__ float bf2f(unsigned short h){
    return __uint_as_float(((unsigned int)h)<<16);
}
__device__ __forceinline__ void split_bf(float x, unsigned short &hi, unsigned short &lo){
    hi = f2bf(x);
    lo = f2bf(x - bf2f(hi));
}
__device__ __forceinline__ uint4 pack8(const unsigned short* s){
    uint4 u;
    u.x = (unsigned)s[0] | ((unsigned)s[1]<<16);
    u.y = (unsigned)s[2] | ((unsigned)s[3]<<16);
    u.z = (unsigned)s[4] | ((unsigned)s[5]<<16);
    u.w = (unsigned)s[6] | ((unsigned)s[7]<<16);
    return u;
}

// ---------------------------------------------------------------------------
// Counter-based AGENT-scope group barrier — empirically the fastest variant
// (r5/r7: 3.15us/step word incl. stage+compute; r6's epoch-flag was slower).
__device__ __forceinline__ void group_barrier(int* p, int members, int tid) {
    __syncthreads();   // drains vmcnt(0): all threads' stores complete
    if (tid == 0) {
        __hip_atomic_fetch_add(p, 1, __ATOMIC_RELAXED, __HIP_MEMORY_SCOPE_AGENT);
        int it = 0;
        while (__hip_atomic_load(p, __ATOMIC_RELAXED, __HIP_MEMORY_SCOPE_AGENT) < members) {
            __builtin_amdgcn_s_sleep(1);
            if (++it > (1<<22)) break;   // safety: degrade, don't hang
        }
    }
    __builtin_amdgcn_fence(__ATOMIC_ACQUIRE, "workgroup");  // compile-order only
    __syncthreads();
}

// self-test pattern: round 1 is the bitwise inverse of round 0, so a stale
// read (L1, foreign L2, or previous launch) can never match both rounds.
__device__ __forceinline__ unsigned tpat(int bid, int tid, int r) {
    unsigned v = (unsigned)bid * 1315423911u ^ (unsigned)tid * 2654435761u ^ 0x9E3779B9u;
    return r ? ~v : v;
}

// ---------------------------------------------------------------------------
__global__ void zero_f4(float4* __restrict__ p, int n) {
    int i = blockIdx.x * 256 + threadIdx.x;
    if (i < n) p[i] = make_float4(0.f, 0.f, 0.f, 0.f);
}

// ---------------------------------------------------------------------------
// X (32768x768 fp32) -> hi/lo bf16 frag-swizzled blocks.
__global__ void prep_x(const float* __restrict__ X, unsigned short* __restrict__ Xsw) {
    int idx = blockIdx.x * 256 + threadIdx.x;
    int gblk = idx >> 6, ln = idx & 63;
    int mt = gblk / 24, kb = gblk - mt * 24;
    int m = mt * 16 + (ln & 15);
    int k = kb * 32 + (ln >> 4) * 8;
    const float* xp = X + (size_t)m * 768 + k;
    unsigned short hi[8], lo[8];
#pragma unroll
    for (int e = 0; e < 8; e += 4) {
        float4 v = *(const float4*)(xp + e);
        split_bf(v.x, hi[e+0], lo[e+0]);
        split_bf(v.y, hi[e+1], lo[e+1]);
        split_bf(v.z, hi[e+2], lo[e+2]);
        split_bf(v.w, hi[e+3], lo[e+3]);
    }
    *(uint4*)&Xsw[(size_t)gblk*1024 + ln*8]       = pack8(hi);
    *(uint4*)&Xsw[(size_t)gblk*1024 + 512 + ln*8] = pack8(lo);
}

// ---------------------------------------------------------------------------
__global__ void prep_wih_sw(const float* __restrict__ Wf, const float* __restrict__ Wb,
                            unsigned short* __restrict__ Wsw) {
    int idx = blockIdx.x * 256 + threadIdx.x;
    int gblk = idx >> 6, ln = idx & 63;
    int dir = gblk / 1536;
    int rem = gblk - dir * 1536;
    int ntile = rem / 24, kb = rem - ntile * 24;
    int j = ntile * 16 + (ln & 15);
    int k = kb * 32 + (ln >> 4) * 8;
    const float* wp = (dir ? Wb : Wf) + (size_t)j * 768 + k;
    unsigned short hi[8], lo[8];
#pragma unroll
    for (int e = 0; e < 8; e += 4) {
        float4 v = *(const float4*)(wp + e);
        split_bf(v.x, hi[e+0], lo[e+0]);
        split_bf(v.y, hi[e+1], lo[e+1]);
        split_bf(v.z, hi[e+2], lo[e+2]);
        split_bf(v.w, hi[e+3], lo[e+3]);
    }
    *(uint4*)&Wsw[(size_t)gblk*1024 + ln*8]       = pack8(hi);
    *(uint4*)&Wsw[(size_t)gblk*1024 + 512 + ln*8] = pack8(lo);
}

// ---------------------------------------------------------------------------
// Word W_hh images: per (dir, u0t): [hi: 4g x 16u x 264][lo: same].
__global__ void prep_whh(const float* __restrict__ Wf, const float* __restrict__ Wb,
                         unsigned short* __restrict__ Wimg) {
    int idx = blockIdx.x * 256 + threadIdx.x;
    if (idx >= 524288) return;
    int dir = idx >> 18;
    int r   = idx & 262143;
    int u0t = r >> 14;
    int g   = (r >> 12) & 3;
    int u   = (r >> 8) & 15;
    int k   = r & 255;
    const float* W = dir ? Wb : Wf;
    float v = W[(size_t)(g*256 + u0t*16 + u) * 256 + k];
    unsigned short hi, lo; split_bf(v, hi, lo);
    size_t base = (size_t)(dir*16 + u0t) * 34816;
    Wimg[base + (g*16 + u)*264 + k]         = hi;
    Wimg[base + 16896 + (g*16 + u)*264 + k] = lo;
}

// ---------------------------------------------------------------------------
// FALLBACK ONLY: transpose sentence-level W_hh -> Wt[dir][k][j]
__global__ void transpose_whh(const float* __restrict__ Wf, const float* __restrict__ Wb,
                              float* __restrict__ Wt) {
    int idx = blockIdx.x * 256 + threadIdx.x;
    if (idx >= 524288) return;
    int dir = idx >> 18;
    int rem = idx & 262143;
    int k = rem >> 10;
    int j = rem & 1023;
    const float* Wp = dir ? Wb : Wf;
    Wt[idx] = Wp[j * 256 + k];
}

// ---------------------------------------------------------------------------
// Word input projection: split-bf16 MFMA, t-major epilogue, XCD-band block
// remap (r8-vs-r9 A/B measured it ~15us faster than the natural mapping;
// pure bijection, correctness mapping-independent).
__global__ __launch_bounds__(256, 2) void proj_mfma(
    const unsigned short* __restrict__ Xsw,
    const unsigned short* __restrict__ Wihsw,
    const float* __restrict__ bfw, const float* __restrict__ bbw,
    float* __restrict__ Of, float* __restrict__ Ob)
{
    __shared__ unsigned short lds[24576];
    const int tid = threadIdx.x;
    const int d   = blockIdx.x + (blockIdx.y << 4);   // 0..2047 linear id
    const int mt  = ((d & 7) << 4) | ((d >> 7) & 15); // XCD band of 16 mt
    const int nt16 = (d >> 3) & 15;
    const int sel = nt16 >> 3;
    const int ntl = nt16 & 7;
    const float* bias = sel ? bbw : bfw;
    float* Op = sel ? Ob : Of;
    const int wv = tid >> 6, ln = tid & 63;
    const int c = ln & 15, q = ln >> 4;

    f32x4 acc[4][8];
#pragma unroll
    for (int i = 0; i < 4; i++)
#pragma unroll
        for (int j = 0; j < 8; j++) acc[i][j] = f32x4{0.f,0.f,0.f,0.f};

    const unsigned short* Abase = Xsw + (size_t)(mt*16) * 24 * 1024;
    const unsigned short* Bbase = Wihsw + (size_t)(sel*64 + ntl*8) * 24 * 1024;

#pragma unroll 1
    for (int kb = 0; kb < 24; kb++) {
        __syncthreads();
#pragma unroll
        for (int jj = 0; jj < 12; jj++) {
            int cc = wv + 4*jj;
            int isB = (cc >= 32);
            int blk = isB ? ((cc - 32) >> 1) : (cc >> 1);
            int half = cc & 1;
            const unsigned short* src = (isB ? Bbase : Abase)
                                        + (size_t)(blk*24 + kb)*1024 + half*512 + ln*8;
            unsigned short* dst = lds + (isB ? 16384 : 0) + blk*1024 + half*512 + ln*8;
            __builtin_amdgcn_global_load_lds(
                (const __attribute__((address_space(1))) unsigned int*)src,
                (__attribute__((address_space(3))) unsigned int*)dst, 16, 0, 0);
        }
        __syncthreads();

        bf16x8 bhv[8], blv[8];
#pragma unroll
        for (int cb = 0; cb < 8; cb++) {
            bhv[cb] = *(const bf16x8*)&lds[16384 + cb*1024 + ln*8];
            blv[cb] = *(const bf16x8*)&lds[16384 + cb*1024 + 512 + ln*8];
        }
#pragma unroll
        for (int rb = 0; rb < 4; rb++) {
            int it = wv*4 + rb;
            bf16x8 ah = *(const bf16x8*)&lds[it*1024 + ln*8];
            bf16x8 al = *(const bf16x8*)&lds[it*1024 + 512 + ln*8];
#pragma unroll
            for (int cb = 0; cb < 8; cb++) {
                acc[rb][cb] = __builtin_amdgcn_mfma_f32_16x16x32_bf16(ah, bhv[cb], acc[rb][cb], 0,0,0);
                acc[rb][cb] = __builtin_amdgcn_mfma_f32_16x16x32_bf16(ah, blv[cb], acc[rb][cb], 0,0,0);
                acc[rb][cb] = __builtin_amdgcn_mfma_f32_16x16x32_bf16(al, bhv[cb], acc[rb][cb], 0,0,0);
            }
        }
    }

#pragma unroll
    for (int rb = 0; rb < 4; rb++) {
        int mbase = mt*256 + (wv*4 + rb)*16 + q*4;
#pragma unroll
        for (int cb = 0; cb < 8; cb++) {
            int j = ntl*128 + cb*16 + c;
            float bv = bias[j];
#pragma unroll
            for (int reg = 0; reg < 4; reg++) {
                int m = mbase + reg;
                int tt = m & 127, nn = m >> 7;
                Op[(size_t)(tt*256 + nn)*1024 + j] = acc[rb][cb][reg] + bv;
            }
        }
    }
}

// ---------------------------------------------------------------------------
// PERSISTENT word recurrence (r7/r10 config: 406us measured). PLAIN launch;
// per-step sync = counter barrier; producers agent atomic stores; consumer
// fast path = global_load_lds aux=0x11 (L1+L2 bypass, reads L3), self-tested
// at startup; fallback = 8B agent atomics. Pool norm fused.
__global__ __launch_bounds__(256, 1) void word_recur(
    const float* __restrict__ Gf, const float* __restrict__ Gb,
    const unsigned short* __restrict__ Wimg,
    unsigned short* __restrict__ hA, unsigned short* __restrict__ hB,
    const int* __restrict__ mask,
    float* __restrict__ pooled, int* __restrict__ cnt,
    int* __restrict__ pf, unsigned int* __restrict__ tstg)
{
    extern __shared__ char ldsbuf[];
    unsigned short* Hl = (unsigned short*)ldsbuf;            // 36864 B
    float* gex   = (float*)(ldsbuf + 36864);                 // 9216 B  [4][16][36]
    int*   mk_lds= (int*)(ldsbuf + 46080);                   // 16384 B [32 seq][128 t]
    // total 62464 B

    const int tid = threadIdx.x;
    const int bid = blockIdx.x;
    const int dir = (bid >> 3) & 1;
    const int nt  = bid & 7;
    const int u0t = bid >> 4;
    const int grp = bid & 15;
    const float* G = dir ? Gb : Gf;

    const int wv = tid >> 6, ln = tid & 63;
    const int c = ln & 15, q = ln >> 4;

    int* mycnt = cnt + grp * 136;   // slots 0..126 = steps, 127..131 = self-test

    // ---- self-test of the fast consumer path (slots 127..131):
    //      agent atomic store -> agent barrier -> load_lds aux=0x11 ----
    bool fast;
    {
        unsigned* tl = (unsigned*)ldsbuf;         // [4][256] staged partner data
        int* oks = (int*)(ldsbuf + 4096);         // [256]
        int okl = 1;
#pragma unroll 1
        for (int r = 0; r < 2; r++) {
            __hip_atomic_store(&tstg[bid*256 + tid], tpat(bid, tid, r),
                               __ATOMIC_RELAXED, __HIP_MEMORY_SCOPE_AGENT);
            group_barrier(mycnt + 127 + 2*r, 16, tid);          // all wrote
            {
                int pbid = grp + 16*((u0t + 1 + wv) & 15);
                __builtin_amdgcn_global_load_lds(
                    (const __attribute__((address_space(1))) unsigned int*)
                        ((const char*)(tstg + pbid*256) + ln*16),
                    (__attribute__((address_space(3))) unsigned int*)(ldsbuf + wv*1024),
                    16, 0, 0x11 /* SC0|SC1: L1+L2 bypass */);
            }
            __syncthreads();
#pragma unroll
            for (int w2 = 0; w2 < 4; w2++) {
                int pb2 = grp + 16*((u0t + 1 + w2) & 15);
                okl &= (tl[w2*256 + tid] == tpat(pb2, tid, r)) ? 1 : 0;
            }
            group_barrier(mycnt + 128 + 2*r, 16, tid);          // all read
        }
        oks[tid] = okl;
        __syncthreads();
        if (tid == 0) {
            int o = 1;
            for (int i = 0; i < 256; i++) o &= oks[i];
            __hip_atomic_store(&pf[bid], o, __ATOMIC_RELAXED, __HIP_MEMORY_SCOPE_AGENT);
        }
        group_barrier(mycnt + 131, 16, tid);
        int f = 1;
#pragma unroll 1
        for (int k = 0; k < 16; k++)
            f &= __hip_atomic_load(&pf[grp + 16*k],
                                   __ATOMIC_RELAXED, __HIP_MEMORY_SCOPE_AGENT);
        fast = (f != 0);
    }

    // ---- one-time: stage mask rows into LDS ----
    {
        const char* msrc = (const char*)(mask + nt*32*128);
#pragma unroll
        for (int j = 0; j < 4; j++) {
            int i = wv + 4*j;
            __builtin_amdgcn_global_load_lds(
                (const __attribute__((address_space(1))) unsigned int*)(msrc + i*1024 + ln*16),
                (__attribute__((address_space(3))) unsigned int*)(((char*)mk_lds) + i*1024), 16, 0, 0);
        }
    }
    // ---- one-time: W fragments (loop-invariant) ----
    const unsigned short* wbase = Wimg + (size_t)(dir*16 + u0t) * 34816;
    bf16x8 wh_[8], wlo[8];
#pragma unroll
    for (int kb = 0; kb < 8; kb++) {
        wh_[kb] = *(const bf16x8*)&wbase[(wv*16 + c)*264 + kb*32 + q*8];
        wlo[kb] = *(const bf16x8*)&wbase[16896 + (wv*16 + c)*264 + kb*32 + q*8];
    }

    // cell-update mapping: thread owns (seq nl, unit pair up)
    const int nl  = tid >> 3;            // 0..31
    const int up  = tid & 7;             // 0..7 -> units 2*up, 2*up+1
    const int u0  = up*2;
    const int ug0 = u0t*16 + u0;
    const int n   = nt*32 + nl;

    float c0 = 0.f, c1 = 0.f, p0 = 0.f, p1 = 0.f;

    // G prefetch for t = 0
    float2 gp[4];
    {
        const int te0 = dir ? 127 : 0;
        const float* Ga = G + (size_t)(te0*256 + n)*1024 + ug0;
#pragma unroll
        for (int g = 0; g < 4; g++) gp[g] = *(const float2*)&Ga[g*256];
    }

#pragma unroll 1
    for (int t = 0; t < 128; ++t) {
        const int te = dir ? (127 - t) : t;
        const unsigned short* hin = (t & 1) ? hB : hA;
        unsigned short* hout = ((t & 1) ? hA : hB) + (size_t)(dir*8 + nt) * 18432;

        // stage h image (36 KB)
        if (fast) {
            const char* hsrc = (const char*)(hin + (size_t)(dir*8 + nt) * 18432);
#pragma unroll
            for (int j = 0; j < 9; j++) {
                int i = wv + 4*j;
                __builtin_amdgcn_global_load_lds(
                    (const __attribute__((address_space(1))) unsigned int*)(hsrc + i*1024 + ln*16),
                    (__attribute__((address_space(3))) unsigned int*)(ldsbuf + i*1024),
                    16, 0, 0x11 /* SC0|SC1 */);
            }
        } else {
            const unsigned long long* hsrc =
                (const unsigned long long*)(hin + (size_t)(dir*8 + nt) * 18432);
            unsigned long long* hdst = (unsigned long long*)ldsbuf;
#pragma unroll
            for (int j = 0; j < 18; j++) {
                unsigned long long v = __hip_atomic_load(hsrc + tid + 256*j,
                        __ATOMIC_RELAXED, __HIP_MEMORY_SCOPE_AGENT);
                hdst[tid + 256*j] = v;
            }
        }
        __syncthreads();   // staging complete

        f32x4 acc[2];
        acc[0] = f32x4{0.f,0.f,0.f,0.f};
        acc[1] = f32x4{0.f,0.f,0.f,0.f};
#pragma unroll
        for (int kb = 0; kb < 8; kb++) {
#pragma unroll
            for (int sb = 0; sb < 2; sb++) {
                bf16x8 bh = *(const bf16x8*)&Hl[(sb*16 + c)*264 + kb*32 + q*8];
                bf16x8 bl = *(const bf16x8*)&Hl[8448 + (sb*16 + c)*264 + kb*32 + q*8];
                acc[sb] = __builtin_amdgcn_mfma_f32_16x16x32_bf16(wh_[kb], bh, acc[sb], 0, 0, 0);
                acc[sb] = __builtin_amdgcn_mfma_f32_16x16x32_bf16(wh_[kb], bl, acc[sb], 0, 0, 0);
                acc[sb] = __builtin_amdgcn_mfma_f32_16x16x32_bf16(wlo[kb], bh, acc[sb], 0, 0, 0);
            }
        }
#pragma unroll
        for (int sb = 0; sb < 2; sb++)
#pragma unroll
            for (int reg = 0; reg < 4; reg++)
                gex[(wv*16 + q*4 + reg)*36 + sb*16 + c] = acc[sb][reg];
        __syncthreads();

        // G prefetch for t+1: issued here so HBM latency hides under the
        // cell-update transcendentals.
        float2 gpn[4];
        if (t < 127) {
            const int te1 = dir ? (126 - t) : (t + 1);
            const float* Ga = G + (size_t)(te1*256 + n)*1024 + ug0;
#pragma unroll
            for (int g = 0; g < 4; g++) gpn[g] = *(const float2*)&Ga[g*256];
        }

        // ---- cell update: (nl, u0) and (nl, u0+1), state in registers ----
        const int mk = mk_lds[nl*128 + te];
        float iv0 = gex[(0*16 + u0)*36 + nl] + gp[0].x;
        float fv0 = gex[(1*16 + u0)*36 + nl] + gp[1].x;
        float gv0 = gex[(2*16 + u0)*36 + nl] + gp[2].x;
        float ov0 = gex[(3*16 + u0)*36 + nl] + gp[3].x;
        float iv1 = gex[(0*16 + u0+1)*36 + nl] + gp[0].y;
        float fv1 = gex[(1*16 + u0+1)*36 + nl] + gp[1].y;
        float gv1 = gex[(2*16 + u0+1)*36 + nl] + gp[2].y;
        float ov1 = gex[(3*16 + u0+1)*36 + nl] + gp[3].y;
        float cn0 = sigmoidf_(fv0)*c0 + sigmoidf_(iv0)*tanhf(gv0);
        float hn0 = sigmoidf_(ov0)*tanhf(cn0);
        float cn1 = sigmoidf_(fv1)*c1 + sigmoidf_(iv1)*tanhf(gv1);
        float hn1 = sigmoidf_(ov1)*tanhf(cn1);
        c0 = cn0; c1 = cn1;
        if (mk) { p0 += hn0; p1 += hn1; }
        if (t != 127) {
            unsigned short h0h, h0l, h1h, h1l;
            split_bf(hn0, h0h, h0l);
            split_bf(hn1, h1h, h1l);
            unsigned int dhi = (unsigned)h0h | ((unsigned)h1h << 16);
            unsigned int dlo = (unsigned)h0l | ((unsigned)h1l << 16);
            unsigned int* hw = (unsigned int*)hout;
            // ALWAYS write-through to the coherent point (both paths read it)
            __hip_atomic_store(&hw[nl*132 + u0t*8 + up], dhi,
                               __ATOMIC_RELAXED, __HIP_MEMORY_SCOPE_AGENT);
            __hip_atomic_store(&hw[4224 + nl*132 + u0t*8 + up], dlo,
                               __ATOMIC_RELAXED, __HIP_MEMORY_SCOPE_AGENT);
        }

        if (t < 127) {
            group_barrier(mycnt + t, 16, tid);
#pragma unroll
            for (int g = 0; g < 4; g++) gp[g] = gpn[g];
        }
    }

    // ---- fused pool normalization: emb = sum(h*m)/max(cnt,1) ----
    int cntN = 0;
#pragma unroll 1
    for (int te2 = 0; te2 < 128; ++te2) cntN += mk_lds[nl*128 + te2];
    float inv = 1.0f / fmaxf((float)cntN, 1.0f);
    *(float2*)&pooled[n*512 + dir*256 + ug0] = make_float2(p0*inv, p1*inv);
}

// ---------------------------------------------------------------------------
// FALLBACK ONLY: original per-step word kernel.
__global__ __launch_bounds__(256) void word_step_mfma(
    const float* __restrict__ Gf, const float* __restrict__ Gb,
    const unsigned short* __restrict__ Wimg,
    const unsigned short* __restrict__ hin_img,
    unsigned short* __restrict__ hout_img,
    const int* __restrict__ mask,
    float* __restrict__ c_st, float* __restrict__ pooled, int t)
{
    extern __shared__ char ldsbuf[];
    unsigned short* Wl = (unsigned short*)ldsbuf;
    unsigned short* Hl = Wl + 34816;
    float* gex = (float*)(ldsbuf + 69632 + 36864);

    const int tid = threadIdx.x;
    const int bid = blockIdx.x;
    const int dir = bid >> 7;
    const int u0t = (bid >> 3) & 15;
    const int nt  = bid & 7;
    const int te  = dir ? (127 - t) : t;
    const float* G = dir ? Gb : Gf;

    const int wv = tid >> 6, ln = tid & 63;
    const int c = ln & 15, q = ln >> 4;

    {
        const char* wsrc = (const char*)(Wimg + (size_t)(dir*16 + u0t) * 34816);
        const char* hsrc = (const char*)(hin_img + (size_t)(dir*8 + nt) * 18432);
        char* wdst = (char*)Wl;
        char* hdst = (char*)Hl;
#pragma unroll
        for (int j = 0; j < 17; j++) {
            int i = wv + 4*j;
            __builtin_amdgcn_global_load_lds(
                (const __attribute__((address_space(1))) unsigned int*)(wsrc + i*1024 + ln*16),
                (__attribute__((address_space(3))) unsigned int*)(wdst + i*1024), 16, 0, 0);
        }
#pragma unroll
        for (int j = 0; j < 9; j++) {
            int i = wv + 4*j;
            __builtin_amdgcn_global_load_lds(
                (const __attribute__((address_space(1))) unsigned int*)(hsrc + i*1024 + ln*16),
                (__attribute__((address_space(3))) unsigned int*)(hdst + i*1024), 16, 0, 0);
        }
    }

    const int uu = tid & 15;
    const int np = tid >> 4;
    const int uglob = u0t*16 + uu;
    const int n_a = nt*32 + np*2;
    float gpre[8]; int mk0, mk1; float cold0, cold1, pold0, pold1;
    {
        const float* Ga = G + (size_t)(te*256 + n_a)*1024 + uglob;
        const float* Gc = Ga + 1024;
#pragma unroll
        for (int g = 0; g < 4; g++) { gpre[g] = Ga[g*256]; gpre[4+g] = Gc[g*256]; }
        mk0 = mask[n_a*128 + te];
        mk1 = mask[(n_a + 1)*128 + te];
        cold0 = c_st[dir*65536 + n_a*256 + uglob];
        cold1 = c_st[dir*65536 + (n_a + 1)*256 + uglob];
        pold0 = pooled[n_a*512 + dir*256 + uglob];
        pold1 = pooled[(n_a + 1)*512 + dir*256 + uglob];
    }
    __syncthreads();

    f32x4 acc[2];
    acc[0] = f32x4{0.f,0.f,0.f,0.f};
    acc[1] = f32x4{0.f,0.f,0.f,0.f};
#pragma unroll
    for (int kb = 0; kb < 8; kb++) {
        bf16x8 ahh = *(const bf16x8*)&Wl[(wv*16 + c)*264 + kb*32 + q*8];
        bf16x8 all_ = *(const bf16x8*)&Wl[16896 + (wv*16 + c)*264 + kb*32 + q*8];
#pragma unroll
        for (int sb = 0; sb < 2; sb++) {
            bf16x8 bh = *(const bf16x8*)&Hl[(sb*16 + c)*264 + kb*32 + q*8];
            bf16x8 bl = *(const bf16x8*)&Hl[8448 + (sb*16 + c)*264 + kb*32 + q*8];
            acc[sb] = __builtin_amdgcn_mfma_f32_16x16x32_bf16(ahh, bh, acc[sb], 0, 0, 0);
            acc[sb] = __builtin_amdgcn_mfma_f32_16x16x32_bf16(ahh, bl, acc[sb], 0, 0, 0);
            acc[sb] = __builtin_amdgcn_mfma_f32_16x16x32_bf16(all_, bh, acc[sb], 0, 0, 0);
        }
    }
#pragma unroll
    for (int sb = 0; sb < 2; sb++)
#pragma unroll
        for (int reg = 0; reg < 4; reg++)
            gex[(wv*16 + q*4 + reg)*36 + sb*16 + c] = acc[sb][reg];
    __syncthreads();

    unsigned short* hout = hout_img + (size_t)(dir*8 + nt) * 18432;
    {
        int nl = np*2;
        float iv = gex[(0*16 + uu)*36 + nl] + gpre[0];
        float fv = gex[(1*16 + uu)*36 + nl] + gpre[1];
        float gv = gex[(2*16 + uu)*36 + nl] + gpre[2];
        float ov = gex[(3*16 + uu)*36 + nl] + gpre[3];
        float cn = sigmoidf_(fv)*cold0 + sigmoidf_(iv)*tanhf(gv);
        float hn = sigmoidf_(ov)*tanhf(cn);
        c_st[dir*65536 + n_a*256 + uglob] = cn;
        unsigned short hh, hl; split_bf(hn, hh, hl);
        hout[nl*264 + uglob] = hh;
        hout[8448 + nl*264 + uglob] = hl;
        if (mk0) pooled[n_a*512 + dir*256 + uglob] = pold0 + hn;
    }
    {
        int nl = np*2 + 1;
        float iv = gex[(0*16 + uu)*36 + nl] + gpre[4];
        float fv = gex[(1*16 + uu)*36 + nl] + gpre[5];
        float gv = gex[(2*16 + uu)*36 + nl] + gpre[6];
        float ov = gex[(3*16 + uu)*36 + nl] + gpre[7];
        float cn = sigmoidf_(fv)*cold1 + sigmoidf_(iv)*tanhf(gv);
        float hn = sigmoidf_(ov)*tanhf(cn);
        c_st[dir*65536 + (n_a+1)*256 + uglob] = cn;
        unsigned short hh, hl; split_bf(hn, hh, hl);
        hout[nl*264 + uglob] = hh;
        hout[8448 + nl*264 + uglob] = hl;
        if (mk1) pooled[(n_a+1)*512 + dir*256 + uglob] = pold1 + hn;
    }
}

// ---------------------------------------------------------------------------
// fp32 input-projection GEMM (sentence level), unchanged.
__global__ __launch_bounds__(256) void gemm_proj(
    const float* __restrict__ A, int M, int K,
    const float* __restrict__ Wf, const float* __restrict__ Wb,
    const float* __restrict__ bf, const float* __restrict__ bb,
    float* __restrict__ Of, float* __restrict__ Ob)
{
    __shared__ float As[16][132];
    __shared__ float Bs[16][132];
    const int t = threadIdx.x;
    const int n0 = blockIdx.x * 128;
    const int m0 = blockIdx.y * 128;
    const int sel = (n0 >= 1024);
    const float* Wp = sel ? Wb : Wf;
    const float* bp = sel ? bb : bf;
    float* Op = sel ? Ob : Of;
    const int n0d = n0 & 1023;
    const int tm = t >> 4;
    const int tn = t & 15;

    float acc[8][8];
#pragma unroll
    for (int i = 0; i < 8; i++)
#pragma unroll
        for (int j = 0; j < 8; j++) acc[i][j] = 0.f;

    for (int k0 = 0; k0 < K; k0 += 16) {
        __syncthreads();
#pragma unroll
        for (int rr = 0; rr < 2; rr++) {
            int idx = t + rr * 256;
            int row = idx >> 2, kq = idx & 3;
            float4 v = *(const float4*)&A[(size_t)(m0 + row) * K + k0 + kq * 4];
            As[kq*4+0][row] = v.x; As[kq*4+1][row] = v.y;
            As[kq*4+2][row] = v.z; As[kq*4+3][row] = v.w;
        }
#pragma unroll
        for (int rr = 0; rr < 2; rr++) {
            int idx = t + rr * 256;
            int row = idx >> 2, kq = idx & 3;
            float4 v = *(const float4*)&Wp[(size_t)(n0d + row) * K + k0 + kq * 4];
            Bs[kq*4+0][row] = v.x; Bs[kq*4+1][row] = v.y;
            Bs[kq*4+2][row] = v.z; Bs[kq*4+3][row] = v.w;
        }
        __syncthreads();
#pragma unroll
        for (int k = 0; k < 16; k++) {
            float4 a0 = *(const float4*)&As[k][tm*4];
            float4 a1 = *(const float4*)&As[k][tm*4+64];
            float4 b0 = *(const float4*)&Bs[k][tn*4];
            float4 b1 = *(const float4*)&Bs[k][tn*4+64];
            float av[8] = {a0.x,a0.y,a0.z,a0.w,a1.x,a1.y,a1.z,a1.w};
            float bv[8] = {b0.x,b0.y,b0.z,b0.w,b1.x,b1.y,b1.z,b1.w};
#pragma unroll
            for (int i = 0; i < 8; i++)
#pragma unroll
                for (int j = 0; j < 8; j++)
                    acc[i][j] += av[i] * bv[j];
        }
    }

#pragma unroll
    for (int ih = 0; ih < 2; ih++) {
#pragma unroll
        for (int i = 0; i < 4; i++) {
            int m = m0 + ih*64 + tm*4 + i;
#pragma unroll
            for (int jh = 0; jh < 2; jh++) {
                int col = n0d + jh*64 + tn*4;
                float4 bias4 = *(const float4*)&bp[col];
                float4 r;
                r.x = acc[ih*4+i][jh*4+0] + bias4.x;
                r.y = acc[ih*4+i][jh*4+1] + bias4.y;
                r.z = acc[ih*4+i][jh*4+2] + bias4.z;
                r.w = acc[ih*4+i][jh*4+3] + bias4.w;
                *(float4*)&Op[(size_t)m * 1024 + col] = r;
            }
        }
    }
}

// ---------------------------------------------------------------------------
// FALLBACK ONLY (word fallback path): divide pooled by mask count.
__global__ __launch_bounds__(256) void pool_div(float* __restrict__ pooled,
                                                const int* __restrict__ mask) {
    __shared__ float red[256];
    int n = blockIdx.x, t = threadIdx.x;
    red[t] = (t < 128) ? (float)mask[n*128 + t] : 0.f;
    __syncthreads();
    for (int off = 128; off > 0; off >>= 1) {
        if (t < off) red[t] += red[t + off];
        __syncthreads();
    }
    float inv = 1.0f / fmaxf(red[0], 1.0f);
    pooled[n*512 + t] *= inv;
    pooled[n*512 + 256 + t] *= inv;
}

// ---------------------------------------------------------------------------
// PERSISTENT sentence recurrence (r7/r10 config, measured best). NEW (r11):
// the reference consumes only s[:, -1, :]; its backward half is the hidden
// state after the FIRST reverse step (zero init, input emb[:,31,:]). So bwd
// groups (dir==1) execute exactly one step (s=0, t_eff=31), write final_h,
// and exit before any per-step barrier — the remaining 31 bwd steps are dead
// for the output. Groups never interact cross-group, so this is race-free.
__global__ __launch_bounds__(256) void sent_recur(
    const float* __restrict__ Gsf, const float* __restrict__ Gsb,
    const float* __restrict__ Whf, const float* __restrict__ Whb,
    float* __restrict__ hs0, float* __restrict__ hs1,
    float* __restrict__ final_h, int* __restrict__ cnt,
    int* __restrict__ pf, unsigned int* __restrict__ tstg)
{
    extern __shared__ char sbuf[];
    float* Wlds  = (float*)sbuf;                 // 128 x 260 floats = 133120 B
    float* h_lds = Wlds + 128*260;               // 256
    float* part  = h_lds + 256;                  // 256
    float* ex    = part + 256;                   // 132

    const int tid = threadIdx.x;
    const int bid = blockIdx.x;
    const int dir = (bid >> 3) & 1;
    const int b   = bid & 7;
    const int ut  = bid >> 4;
    const int grp = bid & 15;
    const float* Gs = dir ? Gsb : Gsf;
    const float* Wh = dir ? Whb : Whf;
    const int wv = tid >> 6, ln = tid & 63;

    int* mycnt = cnt + grp * 40;    // slots 0..30 = steps, 31..35 = self-test

    // ---- self-test (slots 31..35), uses Wlds area before W is staged ----
    bool fast;
    {
        unsigned* tl  = (unsigned*)sbuf;          // [4][256]
        int* oks = (int*)(sbuf + 4096);           // [256]
        int okl = 1;
#pragma unroll 1
        for (int r = 0; r < 2; r++) {
            __hip_atomic_store(&tstg[bid*256 + tid], tpat(bid, tid, r) ^ 0x5A5A5A5Au,
                               __ATOMIC_RELAXED, __HIP_MEMORY_SCOPE_AGENT);
            group_barrier(mycnt + 31 + 2*r, 8, tid);
            {
                int pbid = grp + 16*((ut + 1 + wv) & 7);
                __builtin_amdgcn_global_load_lds(
                    (const __attribute__((address_space(1))) unsigned int*)
                        ((const char*)(tstg + pbid*256) + ln*16),
                    (__attribute__((address_space(3))) unsigned int*)(sbuf + wv*1024),
                    16, 0, 0x11 /* SC0|SC1 */);
            }
            __syncthreads();
#pragma unroll
            for (int w2 = 0; w2 < 4; w2++) {
                int pb2 = grp + 16*((ut + 1 + w2) & 7);
                okl &= (tl[w2*256 + tid] == (tpat(pb2, tid, r) ^ 0x5A5A5A5Au)) ? 1 : 0;
            }
            group_barrier(mycnt + 32 + 2*r, 8, tid);
        }
        oks[tid] = okl;
        __syncthreads();
        if (tid == 0) {
            int o = 1;
            for (int i = 0; i < 256; i++) o &= oks[i];
            __hip_atomic_store(&pf[bid], o, __ATOMIC_RELAXED, __HIP_MEMORY_SCOPE_AGENT);
        }
        group_barrier(mycnt + 35, 8, tid);
        int f = 1;
#pragma unroll 1
        for (int k = 0; k < 8; k++)
            f &= __hip_atomic_load(&pf[grp + 16*k],
                                   __ATOMIC_RELAXED, __HIP_MEMORY_SCOPE_AGENT);
        fast = (f != 0);
    }

    // one-time: stage 128 W rows (1 KB each, coalesced)
#pragma unroll
    for (int j = 0; j < 32; j++) {
        int chunk = wv + 4*j;
        int g = chunk >> 5, u2 = chunk & 31;
        const char* src = (const char*)(Wh + (size_t)(g*256 + ut*32 + u2) * 256);
        __builtin_amdgcn_global_load_lds(
            (const __attribute__((address_space(1))) unsigned int*)(src + ln*16),
            (__attribute__((address_space(3))) unsigned int*)((char*)(Wlds + chunk*260)), 16, 0, 0);
    }

    const int jloc = tid & 127, kh = tid >> 7;
    float creg = 0.f;
    const int smax = dir ? 1 : 32;   // bwd: only s=0 (t_eff=31) feeds final_h

#pragma unroll 1
    for (int s = 0; s < smax; ++s) {
        const int t_eff = dir ? (31 - s) : s;
        const float* hin = (s & 1) ? hs1 : hs0;
        float* hout = (s & 1) ? hs0 : hs1;

        // stage h (256 floats = 1 KB)
        if (fast) {
            if (wv == 0)
                __builtin_amdgcn_global_load_lds(
                    (const __attribute__((address_space(1))) unsigned int*)
                        ((const char*)(hin + dir*2048 + b*256) + ln*16),
                    (__attribute__((address_space(3))) unsigned int*)((char*)h_lds),
                    16, 0, 0x11 /* SC0|SC1 */);
        } else if (tid < 128) {
            const unsigned long long* hp =
                (const unsigned long long*)(hin + dir*2048 + b*256);
            unsigned long long v = __hip_atomic_load(hp + tid,
                    __ATOMIC_RELAXED, __HIP_MEMORY_SCOPE_AGENT);
            *(unsigned long long*)&h_lds[tid*2] = v;
        }

        float gsv = 0.f;
        if (tid < 128)
            gsv = Gs[(size_t)(b*32 + t_eff)*1024 + (jloc >> 5)*256 + ut*32 + (jloc & 31)];

        __syncthreads();   // W (s=0) + h staged

        const float* wrow = Wlds + jloc*260 + kh*128;
        const float* hrow = h_lds + kh*128;
        float acc = 0.f;
#pragma unroll
        for (int kc = 0; kc < 32; kc++) {
            float4 w4 = *(const float4*)(wrow + kc*4);
            float4 h4 = *(const float4*)(hrow + kc*4);
            acc += w4.x*h4.x + w4.y*h4.y + w4.z*h4.z + w4.w*h4.w;
        }
        part[tid] = acc;
        __syncthreads();
        if (tid < 128)
            ex[(jloc >> 5)*33 + (jloc & 31)] = part[tid] + part[tid + 128] + gsv;
        __syncthreads();
        if (tid < 32) {
            float iv = ex[0*33 + tid];
            float fv = ex[1*33 + tid];
            float gv = ex[2*33 + tid];
            float ov = ex[3*33 + tid];
            float cn = sigmoidf_(fv)*creg + sigmoidf_(iv)*tanhf(gv);
            float hn = sigmoidf_(ov)*tanhf(cn);
            creg = cn;
            int u = ut*32 + tid;
            // write-through to the coherent point (consumers read via L3)
            __hip_atomic_store((unsigned int*)&hout[dir*2048 + b*256 + u],
                               __float_as_uint(hn),
                               __ATOMIC_RELAXED, __HIP_MEMORY_SCOPE_AGENT);
            if (t_eff == 31) final_h[b*512 + dir*256 + u] = hn;
        }
        if (s < smax - 1) group_barrier(mycnt + s, 8, tid);
    }
}

// ---------------------------------------------------------------------------
// FALLBACK ONLY: original per-step sentence kernel.
__global__ __launch_bounds__(256) void sent_step(
    const float* __restrict__ Gsf, const float* __restrict__ Gsb,
    const float* __restrict__ Wt,
    const float* __restrict__ h_in, float* __restrict__ h_out,
    float* __restrict__ c_s, float* __restrict__ final_h, int s)
{
    __shared__ float h_lds[256];
    __shared__ float part[256];
    __shared__ float ex[4][33];
    const int tid = threadIdx.x;
    const int bx = blockIdx.x;
    const int dir = bx >> 6;
    const int rb = bx & 63;
    const int b = rb >> 3;
    const int ut = rb & 7;
    const int u0 = ut * 32;
    const int t_eff = dir ? (31 - s) : s;
    const float* Gs = dir ? Gsb : Gsf;

    if (tid < 64) {
        float4 v = *(const float4*)&h_in[dir*2048 + b*256 + tid*4];
        *(float4*)&h_lds[tid*4] = v;
    }
    __syncthreads();

    const int kh = tid >> 7;
    const int rr = tid & 127;
    const int g = rr >> 5;
    const int uu = rr & 31;
    const int j = g*256 + u0 + uu;
    const float* wp = Wt + dir*262144 + kh*128*1024 + j;
    float acc = 0.f;
#pragma unroll 8
    for (int k = 0; k < 128; k++)
        acc += wp[k*1024] * h_lds[kh*128 + k];
    part[tid] = acc;
    __syncthreads();
    if (tid < 128) ex[g][uu] = part[tid] + part[tid + 128];
    __syncthreads();

    if (tid < 32) {
        int u = u0 + tid;
        size_t gb = (size_t)(b*32 + t_eff)*1024 + u;
        float iv = ex[0][tid] + Gs[gb];
        float fv = ex[1][tid] + Gs[gb + 256];
        float gv = ex[2][tid] + Gs[gb + 512];
        float ov = ex[3][tid] + Gs[gb + 768];
        int ci = dir*2048 + b*256 + u;
        float cold = c_s[ci];
        float cn = sigmoidf_(fv)*cold + sigmoidf_(iv)*tanhf(gv);
        float hn = sigmoidf_(ov)*tanhf(cn);
        c_s[ci] = cn;
        h_out[ci] = hn;
        if (t_eff == 31) final_h[b*512 + dir*256 + u] = hn;
    }
}

// ---------------------------------------------------------------------------
__global__ __launch_bounds__(256) void logits_k(const float* __restrict__ fh,
                                                const float* __restrict__ cw,
                                                const float* __restrict__ cb,
                                                float* __restrict__ out) {
    __shared__ float red[256];
    int tid = threadIdx.x;
    int o = tid >> 3;
    int b = o >> 2; int c = o & 3;
    int pp = tid & 7;
    float acc = 0.f;
    const float* fv = fh + b*512 + pp*64;
    const float* wv = cw + c*512 + pp*64;
#pragma unroll 8
    for (int e = 0; e < 64; e++) acc += fv[e]*wv[e];
    red[tid] = acc;
    __syncthreads();
    if (pp == 0) {
        float s = 0.f;
#pragma unroll
        for (int qq = 0; qq < 8; qq++) s += red[o*8 + qq];
        out[o] = s + cb[c];
    }
}

// ---------------------------------------------------------------------------
extern "C" void kernel_launch(void* const* d_in, const int* in_sizes, int n_in,
                              void* d_out, int out_size, void* d_ws, size_t ws_size,
                              hipStream_t stream) {
    const float* X       = (const float*)d_in[0];
    const int*   mask    = (const int*)d_in[1];
    const float* wl_ih_f = (const float*)d_in[2];
    const float* wl_hh_f = (const float*)d_in[3];
    const float* wl_b_f  = (const float*)d_in[4];
    const float* wl_ih_b = (const float*)d_in[5];
    const float* wl_hh_b = (const float*)d_in[6];
    const float* wl_b_b  = (const float*)d_in[7];
    const float* ws_ih_f = (const float*)d_in[8];
    const float* ws_hh_f = (const float*)d_in[9];
    const float* ws_b_f  = (const float*)d_in[10];
    const float* ws_ih_b = (const float*)d_in[11];
    const float* ws_hh_b = (const float*)d_in[12];
    const float* ws_b_b  = (const float*)d_in[13];
    const float* cls_w   = (const float*)d_in[14];
    const float* cls_b   = (const float*)d_in[15];
    float* out = (float*)d_out;
    float* w = (float*)d_ws;
    (void)in_sizes; (void)n_in; (void)out_size; (void)ws_size;

    // workspace layout (float offsets)
    float* Gf     = w;                         // 33,554,432 (t-major [t][n][1024])
    float* Gb     = Gf + 33554432;             // 33,554,432
    float* Gsf    = Gb + 33554432;             // 262,144
    float* Gsb    = Gsf + 262144;              // 262,144
    float* Wt     = Gsb + 262144;              // 524,288 (fallback W^T; main path
                                               //   aliases counters/test buffers)
    int*   cnt_w  = (int*)Wt;                  // 2176 ints (16 grp x 136 slots)
    int*   cnt_s  = cnt_w + 2176;              // 640 ints  (16 grp x 40 slots)
    int*   pf     = cnt_s + 640;               // 256 ints  (per-block pass/fail)
    unsigned int* tstg = (unsigned int*)(pf + 256);  // 65536 ints (self-test)
    float* finalh = Wt + 524288;               // 4,096
    // ---- zero region (contiguous) ----
    float* pooled = finalh + 4096;             // 131,072
    float* c_st   = pooled + 131072;           // 131,072 (fallback only)
    float* hs0    = c_st + 131072;             // 4,096
    float* hs1    = hs0 + 4096;                // 4,096
    float* cs     = hs1 + 4096;                // 4,096 (fallback only)
    unsigned short* hA = (unsigned short*)(cs + 4096);  // 294,912 ushorts
    unsigned short* hB = hA + 294912;                   // 294,912
    unsigned short* Xsw   = hB + 294912;                // 50,331,648 ushorts
    unsigned short* Wihsw = Xsw + 50331648;             // 3,145,728
    unsigned short* Wimg  = Wihsw + 3145728;            // 1,114,112

    zero_f4<<<412, 256, 0, stream>>>((float4*)pooled, 105472);
    // counters: 2176 + 640 = 2816 ints = 704 float4
    zero_f4<<<3, 256, 0, stream>>>((float4*)cnt_w, 704);
    prep_x<<<12288, 256, 0, stream>>>(X, Xsw);
    prep_wih_sw<<<768, 256, 0, stream>>>(wl_ih_f, wl_ih_b, Wihsw);
    prep_whh<<<2048, 256, 0, stream>>>(wl_hh_f, wl_hh_b, Wimg);

    // word input projection (split-bf16 MFMA, XCD-band swizzle, t-major out)
    proj_mfma<<<dim3(16, 128), 256, 0, stream>>>(Xsw, Wihsw, wl_b_f, wl_b_b, Gf, Gb);

    // ---- word recurrence: ONE persistent kernel (plain launch;
    //      co-residency by capacity: 256 blocks @ 62.5KB LDS) ----
    {
        (void)hipGetLastError();   // clear
        word_recur<<<256, 256, 62464, stream>>>(Gf, Gb, Wimg, hA, hB, mask,
                                                pooled, cnt_w, pf, tstg);
        hipError_t e = hipGetLastError();
        if (e != hipSuccess) {
            // fallback: original 128-launch loop + pool_div
            hipFuncSetAttribute((const void*)word_step_mfma,
                                hipFuncAttributeMaxDynamicSharedMemorySize, 115712);
            for (int t = 0; t < 128; t++) {
                const unsigned short* hin = (t & 1) ? hB : hA;
                unsigned short* hout      = (t & 1) ? hA : hB;
                word_step_mfma<<<256, 256, 115712, stream>>>(Gf, Gb, Wimg, hin, hout,
                                                             mask, c_st, pooled, t);
            }
            pool_div<<<256, 256, 0, stream>>>(pooled, mask);
        }
    }

    // sentence input projection (fp32): (256x512) @ (512x2048)
    gemm_proj<<<dim3(16, 2), 256, 0, stream>>>(pooled, 256, 512,
                                               ws_ih_f, ws_ih_b, ws_b_f, ws_b_b,
                                               Gsf, Gsb);

    // ---- sentence recurrence: ONE persistent kernel (plain launch;
    //      128 blocks @ 133KB LDS); bwd groups run exactly one step ----
    {
        hipFuncSetAttribute((const void*)sent_recur,
                            hipFuncAttributeMaxDynamicSharedMemorySize, 135696);
        (void)hipGetLastError();   // clear
        sent_recur<<<128, 256, 135696, stream>>>(Gsf, Gsb, ws_hh_f, ws_hh_b,
                                                 hs0, hs1, finalh, cnt_s,
                                                 pf, tstg);
        hipError_t e = hipGetLastError();
        if (e != hipSuccess) {
            // fallback: transpose + original 32-launch loop
            transpose_whh<<<2048, 256, 0, stream>>>(ws_hh_f, ws_hh_b, Wt);
            for (int s = 0; s < 32; s++) {
                float* hin  = (s & 1) ? hs1 : hs0;
                float* hout = (s & 1) ? hs0 : hs1;
                sent_step<<<128, 256, 0, stream>>>(Gsf, Gsb, Wt, hin, hout, cs, finalh, s);
            }
        }
    }

    logits_k<<<1, 256, 0, stream>>>(finalh, cls_w, cls_b, out);
}